// Round 5
// baseline (613.446 us; speedup 1.0000x reference)
//
#include <hip/hip_runtime.h>
#include <cmath>

// MNEMatch: B pairs of [N,D] fp32; S = x1 @ x2^T per pair; greedy max matching
// (== sort entries desc + scan taking row/col-free entries); out[b]=tanh(sum/N).
#define NN 256
#define DD 384
#define CAPS 2048        // sorted candidate capacity (mean ~1350 at T=40)
#define THRESH 40.0f     // ~2.04 sigma of N(0,384)
#define KCAP 128         // tail fast-path capacity (mean k ~41; 128 = +10 sigma)
#define RSTRIDE 257      // odd stride: LDS reads 2-way conflict-free

typedef unsigned long long ull;
typedef short bf16x8 __attribute__((ext_vector_type(8)));
typedef float f32x4  __attribute__((ext_vector_type(4)));

// ---------------- Kernel 1: batched S = A @ B^T via bf16 MFMA --------------
__device__ __forceinline__ unsigned bfpack2(float lo, float hi) {
  return (__float_as_uint(hi) & 0xFFFF0000u) | (__float_as_uint(lo) >> 16);
}

__global__ __launch_bounds__(256) void gemm_bt_mfma(const float* __restrict__ X1,
                                                    const float* __restrict__ X2,
                                                    float* __restrict__ S) {
  const int pair  = blockIdx.z;
  const int rbase = blockIdx.y * 128;
  const int cbase = blockIdx.x * 64;

  __shared__ unsigned short As[128][40];  // 32 k-vals + pad
  __shared__ unsigned short Bs[64][40];

  const int tid   = threadIdx.x;
  const int lane  = tid & 63;
  const int wave  = tid >> 6;
  const int q     = lane >> 4, mi = lane & 15;

  const int srowA = tid >> 1, halfA = tid & 1;
  const int srowB = tid >> 2, qB    = tid & 3;

  const float* Abase = X1 + (size_t)pair * NN * DD + (size_t)(rbase + srowA) * DD + halfA * 16;
  const float* Bbase = X2 + (size_t)pair * NN * DD + (size_t)(cbase + srowB) * DD + qB * 8;

  f32x4 acc[2][4] = {};

  float4 pa0, pa1, pa2, pa3, pb0, pb1;
  {
    const float4* ap = (const float4*)(Abase);
    const float4* bp = (const float4*)(Bbase);
    pa0 = ap[0]; pa1 = ap[1]; pa2 = ap[2]; pa3 = ap[3];
    pb0 = bp[0]; pb1 = bp[1];
  }

  for (int k0 = 0; k0 < DD; k0 += 32) {
    __syncthreads();
    {
      uint4 w0 = make_uint4(bfpack2(pa0.x,pa0.y), bfpack2(pa0.z,pa0.w),
                            bfpack2(pa1.x,pa1.y), bfpack2(pa1.z,pa1.w));
      uint4 w1 = make_uint4(bfpack2(pa2.x,pa2.y), bfpack2(pa2.z,pa2.w),
                            bfpack2(pa3.x,pa3.y), bfpack2(pa3.z,pa3.w));
      *(uint4*)&As[srowA][halfA*16]     = w0;
      *(uint4*)&As[srowA][halfA*16 + 8] = w1;
      uint4 v0 = make_uint4(bfpack2(pb0.x,pb0.y), bfpack2(pb0.z,pb0.w),
                            bfpack2(pb1.x,pb1.y), bfpack2(pb1.z,pb1.w));
      *(uint4*)&Bs[srowB][qB*8] = v0;
    }
    __syncthreads();
    const int kn = k0 + 32;
    if (kn < DD) {
      const float4* ap = (const float4*)(Abase + kn);
      const float4* bp = (const float4*)(Bbase + kn);
      pa0 = ap[0]; pa1 = ap[1]; pa2 = ap[2]; pa3 = ap[3];
      pb0 = bp[0]; pb1 = bp[1];
    }
    bf16x8 af[2], bf[4];
#pragma unroll
    for (int i = 0; i < 2; ++i) af[i] = *(const bf16x8*)&As[wave*32 + i*16 + mi][q*8];
#pragma unroll
    for (int j = 0; j < 4; ++j) bf[j] = *(const bf16x8*)&Bs[j*16 + mi][q*8];
#pragma unroll
    for (int i = 0; i < 2; ++i)
#pragma unroll
      for (int j = 0; j < 4; ++j)
        acc[i][j] = __builtin_amdgcn_mfma_f32_16x16x32_bf16(af[i], bf[j], acc[i][j], 0, 0, 0);
  }

  float* Sp = S + (size_t)pair * NN * NN;
#pragma unroll
  for (int i = 0; i < 2; ++i)
#pragma unroll
    for (int j = 0; j < 4; ++j)
#pragma unroll
      for (int r2 = 0; r2 < 4; ++r2) {
        const int rowg = rbase + wave*32 + i*16 + q*4 + r2;
        const int colg = cbase + j*16 + mi;
        Sp[(size_t)rowg * NN + colg] = acc[i][j][r2];
      }
}

// ---------------- DPP wave64 argmax (result in lane 63) --------------------
#define DPP_STEP(ctrl, rmask)                                                  \
  {                                                                            \
    int vi  = __float_as_int(v);                                               \
    int v2b = __builtin_amdgcn_update_dpp(vi, vi, (ctrl), (rmask), 0xf, false);\
    int i2  = __builtin_amdgcn_update_dpp(c,  c,  (ctrl), (rmask), 0xf, false);\
    float v2 = __int_as_float(v2b);                                            \
    if (v2 > v || (v2 == v && i2 < c)) { v = v2; c = i2; }                     \
  }

__device__ __forceinline__ void dpp_argmax(float& v, int& c) {
  DPP_STEP(0x111, 0xf)  // row_shr:1
  DPP_STEP(0x112, 0xf)  // row_shr:2
  DPP_STEP(0x114, 0xf)  // row_shr:4
  DPP_STEP(0x118, 0xf)  // row_shr:8
  DPP_STEP(0x142, 0xa)  // row_bcast:15
  DPP_STEP(0x143, 0xc)  // row_bcast:31
}
#undef DPP_STEP

__device__ __forceinline__ float rdlane_f(float v, int l) {
  return __int_as_float(__builtin_amdgcn_readlane(__float_as_int(v), l));
}

// masked full-row argmax over alive cols (fused-fallback slow path only)
__device__ __forceinline__ void rescan_row(const float* __restrict__ Sp, int r,
                                           ull a0, ull a1, ull a2, ull a3,
                                           int lane, float& rv, int& rc) {
  float v = -INFINITY; int c = -1;
#pragma unroll
  for (int j = 0; j < 4; ++j) {
    const int cc = j*64 + lane;
    float x = Sp[(size_t)r * NN + cc];
    ull aj = (j==0) ? a0 : (j==1) ? a1 : (j==2) ? a2 : a3;
    float mv = ((aj >> lane) & 1ull) ? x : -INFINITY;
    if (mv > v) { v = mv; c = cc; }
  }
  dpp_argmax(v, c);
  rv = rdlane_f(v, 63);
  rc = __builtin_amdgcn_readlane(c, 63);
}

// i-th set bit (ascending) of a 256-bit mask; 0 if fewer than i+1 bits set
__device__ __forceinline__ int nth_set4(ull m0, ull m1, ull m2, ull m3, int n) {
  int base = 0; ull m = m0;
  int c = __popcll(m);
  if (n >= c) { n -= c; m = m1; base = 64; c = __popcll(m);
    if (n >= c) { n -= c; m = m2; base = 128; c = __popcll(m);
      if (n >= c) { n -= c; m = m3; base = 192; } } }
  for (int i = 0; i < n; ++i) m &= m - 1;
  return m ? (base + (int)__builtin_ctzll(m)) : 0;
}

// max+argmax over one compacted LDS row, cols masked by colAlive (fused fb).
__device__ __forceinline__ void row_max_lds(const float* __restrict__ rowp,
                                            ull colAlive, float& rmv, int& rac) {
  float m0 = -INFINITY, m1 = -INFINITY, m2 = -INFINITY, m3 = -INFINITY;
  int   a0 = 0, a1 = 1, a2 = 2, a3 = 3;
#pragma unroll
  for (int j = 0; j < 64; j += 4) {
    const unsigned g = (unsigned)(colAlive >> j);
    float x0 = (g & 1u) ? rowp[j]     : -INFINITY;
    float x1 = (g & 2u) ? rowp[j + 1] : -INFINITY;
    float x2 = (g & 4u) ? rowp[j + 2] : -INFINITY;
    float x3 = (g & 8u) ? rowp[j + 3] : -INFINITY;
    if (x0 > m0) { m0 = x0; a0 = j; }
    if (x1 > m1) { m1 = x1; a1 = j + 1; }
    if (x2 > m2) { m2 = x2; a2 = j + 2; }
    if (x3 > m3) { m3 = x3; a3 = j + 3; }
  }
  float mv = m0; int ai = a0;
  if (m1 > mv) { mv = m1; ai = a1; }
  if (m2 > mv) { mv = m2; ai = a2; }
  if (m3 > mv) { mv = m3; ai = a3; }
  rmv = mv; rac = ai;
}

// masked max+argmax over a FULL 256-col LDS row (stride-RSTRIDE layout).
// Exact tie-break: lowest column wins (4 chains, natural scan order,
// explicit col tie-break at the merge).
__device__ __forceinline__ void row_max_257(const float* __restrict__ rowp,
                                            ull a0, ull a1, ull a2, ull a3,
                                            float& rmv, int& rac) {
  float m0 = -INFINITY, m1 = -INFINITY, m2 = -INFINITY, m3 = -INFINITY;
  int   b0 = 0, b1 = 64, b2 = 128, b3 = 192;
#pragma unroll
  for (int j = 0; j < 64; ++j) {
    float x0 = ((a0 >> j) & 1ull) ? rowp[j]       : -INFINITY;
    float x1 = ((a1 >> j) & 1ull) ? rowp[64 + j]  : -INFINITY;
    float x2 = ((a2 >> j) & 1ull) ? rowp[128 + j] : -INFINITY;
    float x3 = ((a3 >> j) & 1ull) ? rowp[192 + j] : -INFINITY;
    if (x0 > m0) { m0 = x0; b0 = j; }
    if (x1 > m1) { m1 = x1; b1 = 64 + j; }
    if (x2 > m2) { m2 = x2; b2 = 128 + j; }
    if (x3 > m3) { m3 = x3; b3 = 192 + j; }
  }
  float mv = m0; int ai = b0;
  if (m1 > mv || (m1 == mv && b1 < ai)) { mv = m1; ai = b1; }
  if (m2 > mv || (m2 == mv && b2 < ai)) { mv = m2; ai = b2; }
  if (m3 > mv || (m3 == mv && b3 < ai)) { mv = m3; ai = b3; }
  rmv = mv; rac = ai;
}

// per-lane scan of its OWN row over alive cols (k>KCAP safety path only)
__device__ __forceinline__ void scan_own_row(const float* __restrict__ rowp,
                                             ull a0, ull a1, ull a2, ull a3,
                                             float& mv, int& ac) {
  float v = -INFINITY; int c = 0;
#pragma unroll
  for (int g = 0; g < 4; ++g) {
    const ull am = (g==0) ? a0 : (g==1) ? a1 : (g==2) ? a2 : a3;
#pragma unroll 8
    for (int j = 0; j < 64; ++j) {
      if ((am >> j) & 1ull) {
        const float x = rowp[g*64 + j];
        if (x > v) { v = x; c = g*64 + j; }
      }
    }
  }
  mv = v; ac = c;
}

// ---- legacy tail (fused fallback only): serial gather + global rescans ----
__device__ float finish_tail(const float* __restrict__ Sp, float* __restrict__ sub,
                             int lane,
                             ull arow0, ull arow1, ull arow2, ull arow3,
                             ull acol0, ull acol1, ull acol2, ull acol3,
                             int picks, float sum) {
  if (picks >= NN) return sum;
  const int k = NN - picks;
  if (k <= 64) {
    const int myRow = nth_set4(arow0, arow1, arow2, arow3, lane);
    const int myCol = nth_set4(acol0, acol1, acol2, acol3, lane);
    for (int i = 0; i < k; ++i) {
      const int ri = __builtin_amdgcn_readlane(myRow, i);
      float v = 0.0f;
      if (lane < k) v = Sp[(size_t)ri * NN + myCol];
      sub[i * 65 + lane] = v;
    }
    asm volatile("s_waitcnt lgkmcnt(0)" ::: "memory");
    __builtin_amdgcn_wave_barrier();

    const ull fullMask = (k == 64) ? ~0ull : ((1ull << k) - 1ull);
    ull rowAlive = fullMask, colAlive = fullMask;
    float rmv; int rac;
    row_max_lds(&sub[lane * 65], colAlive, rmv, rac);

    for (int it = 0; it < k; ++it) {
      float v = ((rowAlive >> lane) & 1ull) ? rmv : -INFINITY;
      int c = lane;
      dpp_argmax(v, c);
      const int rstar = __builtin_amdgcn_readlane(c, 63);
      sum += rdlane_f(v, 63);
      const int cstar = __builtin_amdgcn_readlane(rac, rstar);
      rowAlive &= ~(1ull << rstar);
      colAlive &= ~(1ull << cstar);
      const bool stale = ((rowAlive >> lane) & 1ull) && (rac == cstar);
      if (__ballot(stale)) {
        if (stale) row_max_lds(&sub[lane * 65], colAlive, rmv, rac);
      }
    }
  } else {
    float rm[4]; int ra[4];
#pragma unroll
    for (int i = 0; i < 4; ++i) { rm[i] = -INFINITY; ra[i] = -1; }
#pragma unroll
    for (int i = 0; i < 4; ++i) {
      ull m = (i==0) ? arow0 : (i==1) ? arow1 : (i==2) ? arow2 : arow3;
      while (m) {
        const int l = __builtin_ctzll(m); m &= m - 1;
        float rv; int rc;
        rescan_row(Sp, i*64 + l, acol0, acol1, acol2, acol3, lane, rv, rc);
        if (lane == l) { rm[i] = rv; ra[i] = rc; }
      }
    }

    for (int it = picks; it < NN; ++it) {
      float v = rm[0]; int c = lane;
      if (rm[1] > v) { v = rm[1]; c = 64 + lane; }
      if (rm[2] > v) { v = rm[2]; c = 128 + lane; }
      if (rm[3] > v) { v = rm[3]; c = 192 + lane; }
      dpp_argmax(v, c);
      const int   br  = __builtin_amdgcn_readlane(c, 63);
      const float bvv = rdlane_f(v, 63);
      sum += bvv;

      const int bslot = br >> 6, blane = br & 63;
      int myra = ra[0];
      if (bslot == 1) myra = ra[1];
      if (bslot == 2) myra = ra[2];
      if (bslot == 3) myra = ra[3];
      const int bc = __builtin_amdgcn_readlane(myra, blane);

      if (lane == blane) {
        if (bslot == 0) { rm[0] = -INFINITY; ra[0] = -1; }
        if (bslot == 1) { rm[1] = -INFINITY; ra[1] = -1; }
        if (bslot == 2) { rm[2] = -INFINITY; ra[2] = -1; }
        if (bslot == 3) { rm[3] = -INFINITY; ra[3] = -1; }
      }
      const ull cb = ~(1ull << (bc & 63));
      if      (bc < 64)  acol0 &= cb;
      else if (bc < 128) acol1 &= cb;
      else if (bc < 192) acol2 &= cb;
      else               acol3 &= cb;

#pragma unroll
      for (int i = 0; i < 4; ++i) {
        ull m = __ballot(ra[i] == bc);
        while (m) {
          const int l = __builtin_ctzll(m); m &= m - 1;
          float rv; int rc;
          rescan_row(Sp, i*64 + l, acol0, acol1, acol2, acol3, lane, rv, rc);
          if (lane == l) { rm[i] = rv; ra[i] = rc; }
        }
      }
    }
  }
  return sum;
}

// ------ Kernel 2a: collect + bitonic sort (8 waves), keys -> global --------
__global__ __launch_bounds__(512) void collect_sort(const float* __restrict__ S,
                                                    ull* __restrict__ gkeys,
                                                    int* __restrict__ gcnt) {
  const int pair = blockIdx.x;
  const float* Sp = S + (size_t)pair * NN * NN;
  const int tid  = threadIdx.x;
  const int lane = tid & 63;
  const int wv   = tid >> 6;

  __shared__ ull keys[CAPS];           // 16 KB
  __shared__ int lcount;
  if (tid == 0) lcount = 0;
  __syncthreads();

  // ---- collect entries > THRESH ----
  const float4* S4 = (const float4*)Sp;
#pragma unroll 4
  for (int i4 = tid; i4 < NN*NN/4; i4 += 512) {
    float4 x = S4[i4];
    float xv[4] = {x.x, x.y, x.z, x.w};
#pragma unroll
    for (int e = 0; e < 4; ++e) {
      if (xv[e] > THRESH) {
        unsigned b = __float_as_uint(xv[e]);
        unsigned u = (b & 0x80000000u) ? ~b : (b | 0x80000000u);  // monotone asc
        int pos = atomicAdd(&lcount, 1);
        if (pos < CAPS)
          keys[pos] = ((ull)(~u) << 32) | (unsigned)(i4*4 + e);
      }
    }
  }
  __syncthreads();
  int count = lcount;
  if (count > CAPS) count = 0;         // overflow => exact fallback downstream
  for (int i = count + tid; i < CAPS; i += 512) keys[i] = ~0ull;
  __syncthreads();

  // ---- bitonic sort ascending; wave-local 256-elem chunks ----
#define CMPSWAP(I, K)                                                          \
  {                                                                            \
    unsigned ixj = (I) ^ j;                                                    \
    if (ixj > (I)) {                                                           \
      ull a = keys[(I)], b = keys[ixj];                                        \
      bool asc = (((I) & (K)) == 0);                                           \
      if ((a > b) == asc) { keys[(I)] = b; keys[ixj] = a; }                    \
    }                                                                          \
  }

  const unsigned wbase = wv * 256;
  for (unsigned k = 2; k <= 256; k <<= 1)
    for (unsigned j = k >> 1; j > 0; j >>= 1) {
      for (unsigned t = lane; t < 256; t += 64) { unsigned i = wbase + t; CMPSWAP(i, k) }
      __builtin_amdgcn_wave_barrier();
    }
  __syncthreads();
  // k=512: j=256 cross, then local
  { unsigned j = 256; for (unsigned i = tid; i < CAPS; i += 512) CMPSWAP(i, 512) }
  __syncthreads();
  for (unsigned j = 128; j > 0; j >>= 1) {
    for (unsigned t = lane; t < 256; t += 64) { unsigned i = wbase + t; CMPSWAP(i, 512) }
    __builtin_amdgcn_wave_barrier();
  }
  __syncthreads();
  // k=1024: j=512,256 cross, then local
  { unsigned j = 512; for (unsigned i = tid; i < CAPS; i += 512) CMPSWAP(i, 1024) }
  __syncthreads();
  { unsigned j = 256; for (unsigned i = tid; i < CAPS; i += 512) CMPSWAP(i, 1024) }
  __syncthreads();
  for (unsigned j = 128; j > 0; j >>= 1) {
    for (unsigned t = lane; t < 256; t += 64) { unsigned i = wbase + t; CMPSWAP(i, 1024) }
    __builtin_amdgcn_wave_barrier();
  }
  __syncthreads();
  // k=2048: j=1024,512,256 cross, then local
  { unsigned j = 1024; for (unsigned i = tid; i < CAPS; i += 512) CMPSWAP(i, 2048) }
  __syncthreads();
  { unsigned j = 512; for (unsigned i = tid; i < CAPS; i += 512) CMPSWAP(i, 2048) }
  __syncthreads();
  { unsigned j = 256; for (unsigned i = tid; i < CAPS; i += 512) CMPSWAP(i, 2048) }
  __syncthreads();
  for (unsigned j = 128; j > 0; j >>= 1) {
    for (unsigned t = lane; t < 256; t += 64) { unsigned i = wbase + t; CMPSWAP(i, 2048) }
    __builtin_amdgcn_wave_barrier();
  }
#undef CMPSWAP
  __syncthreads();

  for (int i = tid; i < count; i += 512) gkeys[(size_t)pair * CAPS + i] = keys[i];
  if (tid == 0) gcnt[pair] = count;
}

// ------ Kernel 2b: ordered scan (phase 3 only), 1 wave per pair ------------
__global__ __launch_bounds__(64) void scan_match(const ull* __restrict__ gkeys,
                                                 const int* __restrict__ gcnt,
                                                 ull* __restrict__ gmask,
                                                 float* __restrict__ gsum,
                                                 int* __restrict__ gpicks) {
  const int pair = blockIdx.x;
  const int lane = threadIdx.x;
  const int count = gcnt[pair];
  const ull* kp = gkeys + (size_t)pair * CAPS;

  unsigned rowAlive = 0xFu, colAlive = 0xFu;   // 4 rows/cols per lane
  float sum = 0.0f;
  int picks = 0;

  // prefetch first batch
  ull key = ~0ull;
  if (count > 0) { int i0 = (lane < count) ? lane : 0; key = kp[i0]; }

  for (int base = 0; base < count && picks < NN; base += 64) {
    // issue next batch's load before processing current (hides latency)
    ull nkey = ~0ull;
    const int nbase = base + 64;
    if (nbase < count) { int ni = nbase + lane; if (ni >= count) ni = nbase; nkey = kp[ni]; }

    const int flat = (int)(unsigned)key;
    const int r = (flat >> 8) & 255, c = flat & 255;
    const unsigned u = ~(unsigned)(key >> 32);
    const float val = __uint_as_float((u & 0x80000000u) ? (u ^ 0x80000000u) : ~u);
    const bool valid = (base + lane) < count;

    // batch init: fetch alive bits of (r,c) from owning lanes
    const int rbits = __builtin_amdgcn_ds_bpermute((r & 63) << 2, (int)rowAlive);
    const int cbits = __builtin_amdgcn_ds_bpermute((c & 63) << 2, (int)colAlive);
    bool alive = valid && (((rbits >> (r >> 6)) & 1) != 0) && (((cbits >> (c >> 6)) & 1) != 0);

    // per-pick recurrence: ballot -> ctz -> readlane -> compare-kill
    while (true) {
      const ull mb = __ballot(alive);
      if (!mb) break;
      const int t   = __builtin_ctzll(mb);       // lowest lane = sorted order
      const int r_t = __builtin_amdgcn_readlane(r, t);
      const int c_t = __builtin_amdgcn_readlane(c, t);
      sum += rdlane_f(val, t);
      ++picks;
      alive = alive && (r != r_t) && (c != c_t);
      rowAlive &= ~((lane == (r_t & 63) ? 1u : 0u) << (r_t >> 6));
      colAlive &= ~((lane == (c_t & 63) ? 1u : 0u) << (c_t >> 6));
      if (picks == NN) break;
    }
    key = nkey;
  }

  // reconstruct 256-bit masks (8 ballots) and persist state
  ull m[8];
#pragma unroll
  for (int i = 0; i < 4; ++i) m[i]     = __ballot(((rowAlive >> i) & 1u) != 0);
#pragma unroll
  for (int i = 0; i < 4; ++i) m[4 + i] = __ballot(((colAlive >> i) & 1u) != 0);
  if (lane == 0) {
    ull* mp = gmask + (size_t)pair * 8;
#pragma unroll
    for (int i = 0; i < 8; ++i) mp[i] = m[i];
    gsum[pair]   = sum;
    gpicks[pair] = picks;
  }
}

// ------ Kernel 2c: tail greedy, FAST path (k <= KCAP), big-LDS -------------
// 256 threads load the <=128 alive FULL rows into stride-257 LDS (coalesced
// global reads, conflict-free LDS); wave 0 runs the greedy with 2 row-slots
// per lane. Pairs with k > KCAP are left for tail_safe.
__global__ __launch_bounds__(256) void tail_fast(const float* __restrict__ S,
                                                 const ull* __restrict__ gmask,
                                                 const float* __restrict__ gsum,
                                                 const int* __restrict__ gpicks,
                                                 float* __restrict__ out) {
  const int pair = blockIdx.x;
  const int tid  = threadIdx.x;
  const int lane = tid & 63;
  const int wv   = tid >> 6;
  const float* Sp = S + (size_t)pair * NN * NN;

  __shared__ float rows[KCAP * RSTRIDE];   // 131.6 KB

  float sum = gsum[pair];
  const int picks = gpicks[pair];
  if (picks >= NN) {
    if (tid == 0) out[pair] = tanhf(sum / (float)NN);
    return;
  }
  const int k = NN - picks;
  if (k > KCAP) return;                    // tail_safe handles (unreachable statistically)

  const ull* mp = gmask + (size_t)pair * 8;
  const ull arow0 = mp[0], arow1 = mp[1], arow2 = mp[2], arow3 = mp[3];
  ull acol0 = mp[4], acol1 = mp[5], acol2 = mp[6], acol3 = mp[7];

  // gather: 2 threads per row slot, 32 float4 global loads each, scalar LDS writes
  {
    const int slot = tid >> 1, half = tid & 1;
    if (slot < k) {
      const int r = nth_set4(arow0, arow1, arow2, arow3, slot);
      const float4* src = (const float4*)(Sp + (size_t)r * NN + half * 128);
      float* dst = &rows[slot * RSTRIDE + half * 128];
#pragma unroll
      for (int i = 0; i < 32; ++i) {
        float4 v = src[i];
        dst[i*4 + 0] = v.x; dst[i*4 + 1] = v.y;
        dst[i*4 + 2] = v.z; dst[i*4 + 3] = v.w;
      }
    }
  }
  __syncthreads();
  if (wv != 0) return;                     // wave 0 finishes alone

  // greedy: lane owns slots lane (lo) and lane+64 (hi); slots ascend by row
  float rmv0 = -INFINITY, rmv1 = -INFINITY;
  int   rac0 = 0, rac1 = 0;
  if (lane < k)
    row_max_257(&rows[lane * RSTRIDE], acol0, acol1, acol2, acol3, rmv0, rac0);
  if (lane + 64 < k)
    row_max_257(&rows[(lane + 64) * RSTRIDE], acol0, acol1, acol2, acol3, rmv1, rac1);

  for (int it = 0; it < k; ++it) {
    float v; int c;
    if (rmv1 > rmv0) { v = rmv1; c = lane + 64; }   // tie -> lo slot (lower row)
    else             { v = rmv0; c = lane; }
    dpp_argmax(v, c);                       // tie-break lowest slot = lowest row
    const int s  = __builtin_amdgcn_readlane(c, 63);
    sum += rdlane_f(v, 63);
    const int wl = s & 63;
    const int colLo = __builtin_amdgcn_readlane(rac0, wl);
    const int colHi = __builtin_amdgcn_readlane(rac1, wl);
    const int colg  = (s >= 64) ? colHi : colLo;    // original col of the pick
    if (lane == wl) { if (s >= 64) rmv1 = -INFINITY; else rmv0 = -INFINITY; }
    { const ull cb = 1ull << (colg & 63); const int cs6 = colg >> 6;
      acol0 &= ~((cs6 == 0) ? cb : 0ull);
      acol1 &= ~((cs6 == 1) ? cb : 0ull);
      acol2 &= ~((cs6 == 2) ? cb : 0ull);
      acol3 &= ~((cs6 == 3) ? cb : 0ull); }
    // stale rows rescan CONCURRENTLY from LDS (exec-masked)
    const bool st0 = (rmv0 > -INFINITY) && (rac0 == colg);
    const bool st1 = (rmv1 > -INFINITY) && (rac1 == colg);
    if (__ballot(st0 || st1)) {
      if (st0) row_max_257(&rows[lane * RSTRIDE], acol0, acol1, acol2, acol3, rmv0, rac0);
      if (st1) row_max_257(&rows[(lane + 64) * RSTRIDE], acol0, acol1, acol2, acol3, rmv1, rac1);
    }
  }

  if (lane == 0) out[pair] = tanhf(sum / (float)NN);
}

// ------ Kernel 2d: tail SAFE path (k > KCAP) — full global greedy ----------
// Statistically unreachable (mean k ~41). If rocprof shows real time here,
// scan_match is under-picking — investigate.
__global__ __launch_bounds__(64) void tail_safe(const float* __restrict__ S,
                                                const ull* __restrict__ gmask,
                                                const float* __restrict__ gsum,
                                                const int* __restrict__ gpicks,
                                                float* __restrict__ out) {
  const int pair = blockIdx.x;
  const int lane = threadIdx.x;
  const float* Sp = S + (size_t)pair * NN * NN;

  float sum = gsum[pair];
  const int picks = gpicks[pair];
  if (picks >= NN) return;                 // handled by tail_fast
  const int k = NN - picks;
  if (k <= KCAP) return;                   // handled by tail_fast

  const ull* mp = gmask + (size_t)pair * 8;
  const ull arow0 = mp[0], arow1 = mp[1], arow2 = mp[2], arow3 = mp[3];
  ull acol0 = mp[4], acol1 = mp[5], acol2 = mp[6], acol3 = mp[7];

  float rm[4]; int ra[4];
#pragma unroll
  for (int i = 0; i < 4; ++i) { rm[i] = -INFINITY; ra[i] = -1; }
  {
    const bool a0 = ((arow0 >> lane) & 1ull) != 0;
    if (a0) scan_own_row(Sp + (size_t)lane * NN, acol0, acol1, acol2, acol3, rm[0], ra[0]);
    const bool a1 = ((arow1 >> lane) & 1ull) != 0;
    if (a1) scan_own_row(Sp + (size_t)(64 + lane) * NN, acol0, acol1, acol2, acol3, rm[1], ra[1]);
    const bool a2 = ((arow2 >> lane) & 1ull) != 0;
    if (a2) scan_own_row(Sp + (size_t)(128 + lane) * NN, acol0, acol1, acol2, acol3, rm[2], ra[2]);
    const bool a3 = ((arow3 >> lane) & 1ull) != 0;
    if (a3) scan_own_row(Sp + (size_t)(192 + lane) * NN, acol0, acol1, acol2, acol3, rm[3], ra[3]);
  }
  for (int it = picks; it < NN; ++it) {
    float v = rm[0]; int c = lane;
    if (rm[1] > v) { v = rm[1]; c = 64 + lane; }
    if (rm[2] > v) { v = rm[2]; c = 128 + lane; }
    if (rm[3] > v) { v = rm[3]; c = 192 + lane; }
    dpp_argmax(v, c);
    const int br = __builtin_amdgcn_readlane(c, 63);
    sum += rdlane_f(v, 63);

    const int bslot = br >> 6, blane = br & 63;
    int myra = ra[0];
    if (bslot == 1) myra = ra[1];
    if (bslot == 2) myra = ra[2];
    if (bslot == 3) myra = ra[3];
    const int bc = __builtin_amdgcn_readlane(myra, blane);

    if (lane == blane) {
      if (bslot == 0) { rm[0] = -INFINITY; ra[0] = -1; }
      if (bslot == 1) { rm[1] = -INFINITY; ra[1] = -1; }
      if (bslot == 2) { rm[2] = -INFINITY; ra[2] = -1; }
      if (bslot == 3) { rm[3] = -INFINITY; ra[3] = -1; }
    }
    { const ull cb = ~(1ull << (bc & 63));
      if      (bc < 64)  acol0 &= cb;
      else if (bc < 128) acol1 &= cb;
      else if (bc < 192) acol2 &= cb;
      else               acol3 &= cb; }

#pragma unroll
    for (int i = 0; i < 4; ++i) {
      const bool st = (ra[i] == bc);
      if (__ballot(st)) {
        if (st) {
          float nv; int nc;
          scan_own_row(Sp + (size_t)(i*64 + lane) * NN, acol0, acol1, acol2, acol3, nv, nc);
          rm[i] = nv; ra[i] = nc;
        }
      }
    }
  }

  if (lane == 0) out[pair] = tanhf(sum / (float)NN);
}

// ------ Fused fallback (used only if workspace can't fit the keys) ---------
__global__ __launch_bounds__(256) void sort_scan_match(const float* __restrict__ S,
                                                       float* __restrict__ out) {
  const int pair = blockIdx.x;
  const float* Sp = S + (size_t)pair * NN * NN;
  const int tid  = threadIdx.x;
  const int lane = tid & 63;
  const int wv   = tid >> 6;

  __shared__ ull keys[CAPS];
  __shared__ float sub[64 * 65];
  __shared__ int lcount;

  if (tid == 0) lcount = 0;
  __syncthreads();

  const float4* S4 = (const float4*)Sp;
#pragma unroll 4
  for (int i4 = tid; i4 < NN*NN/4; i4 += 256) {
    float4 x = S4[i4];
    float xv[4] = {x.x, x.y, x.z, x.w};
#pragma unroll
    for (int e = 0; e < 4; ++e) {
      if (xv[e] > THRESH) {
        unsigned b = __float_as_uint(xv[e]);
        unsigned u = (b & 0x80000000u) ? ~b : (b | 0x80000000u);
        int pos = atomicAdd(&lcount, 1);
        if (pos < CAPS)
          keys[pos] = ((ull)(~u) << 32) | (unsigned)(i4*4 + e);
      }
    }
  }
  __syncthreads();
  int count = lcount;
  if (count > CAPS) count = 0;
  for (int i = count + tid; i < CAPS; i += 256) keys[i] = ~0ull;
  __syncthreads();

#define CMPSWAP(I, K)                                                          \
  {                                                                            \
    unsigned ixj = (I) ^ j;                                                    \
    if (ixj > (I)) {                                                           \
      ull a = keys[(I)], b = keys[ixj];                                        \
      bool asc = (((I) & (K)) == 0);                                           \
      if ((a > b) == asc) { keys[(I)] = b; keys[ixj] = a; }                    \
    }                                                                          \
  }
  const unsigned wbase = wv * 512;
  for (unsigned k = 2; k <= 512; k <<= 1)
    for (unsigned j = k >> 1; j > 0; j >>= 1) {
      for (unsigned t = lane; t < 512; t += 64) { unsigned i = wbase + t; CMPSWAP(i, k) }
      __builtin_amdgcn_wave_barrier();
    }
  __syncthreads();
  { unsigned j = 512; for (unsigned i = tid; i < CAPS; i += 256) CMPSWAP(i, 1024) }
  __syncthreads();
  for (unsigned j = 256; j > 0; j >>= 1) {
    for (unsigned t = lane; t < 512; t += 64) { unsigned i = wbase + t; CMPSWAP(i, 1024) }
    __builtin_amdgcn_wave_barrier();
  }
  __syncthreads();
  { unsigned j = 1024; for (unsigned i = tid; i < CAPS; i += 256) CMPSWAP(i, 2048) }
  __syncthreads();
  { unsigned j = 512; for (unsigned i = tid; i < CAPS; i += 256) CMPSWAP(i, 2048) }
  __syncthreads();
  for (unsigned j = 256; j > 0; j >>= 1) {
    for (unsigned t = lane; t < 512; t += 64) { unsigned i = wbase + t; CMPSWAP(i, 2048) }
    __builtin_amdgcn_wave_barrier();
  }
  __syncthreads();
#undef CMPSWAP

  if (tid >= 64) return;

  ull arow0 = ~0ull, arow1 = ~0ull, arow2 = ~0ull, arow3 = ~0ull;
  ull acol0 = ~0ull, acol1 = ~0ull, acol2 = ~0ull, acol3 = ~0ull;
  float sum = 0.0f;
  int picks = 0;

  for (int base = 0; base < count && picks < NN; base += 64) {
    const ull key = keys[base + lane];
    const int flat = (int)(unsigned)key;
    const int r = (flat >> 8) & 255, c = flat & 255;
    const unsigned u = ~(unsigned)(key >> 32);
    const float val = __uint_as_float((u & 0x80000000u) ? (u ^ 0x80000000u) : ~u);
    const bool valid = (base + lane) < count;

    const ull rs = (r & 128) ? ((r & 64) ? arow3 : arow2) : ((r & 64) ? arow1 : arow0);
    const ull cs = (c & 128) ? ((c & 64) ? acol3 : acol2) : ((c & 64) ? acol1 : acol0);
    bool alive = valid && (((rs >> (r & 63)) & 1ull) != 0) && (((cs >> (c & 63)) & 1ull) != 0);

    while (true) {
      const ull mb = __ballot(alive);
      if (!mb) break;
      const int t   = __builtin_ctzll(mb);
      const int r_t = __builtin_amdgcn_readlane(r, t);
      const int c_t = __builtin_amdgcn_readlane(c, t);
      sum += rdlane_f(val, t);
      ++picks;
      alive = alive && (r != r_t) && (c != c_t);
      {
        const ull rb = 1ull << (r_t & 63); const int rs6 = r_t >> 6;
        arow0 &= ~((rs6 == 0) ? rb : 0ull);
        arow1 &= ~((rs6 == 1) ? rb : 0ull);
        arow2 &= ~((rs6 == 2) ? rb : 0ull);
        arow3 &= ~((rs6 == 3) ? rb : 0ull);
        const ull cb = 1ull << (c_t & 63); const int cs6 = c_t >> 6;
        acol0 &= ~((cs6 == 0) ? cb : 0ull);
        acol1 &= ~((cs6 == 1) ? cb : 0ull);
        acol2 &= ~((cs6 == 2) ? cb : 0ull);
        acol3 &= ~((cs6 == 3) ? cb : 0ull);
      }
      if (picks == NN) break;
    }
  }

  sum = finish_tail(Sp, sub, lane, arow0, arow1, arow2, arow3,
                    acol0, acol1, acol2, acol3, picks, sum);

  if (lane == 0) out[pair] = tanhf(sum / (float)NN);
}

extern "C" void kernel_launch(void* const* d_in, const int* in_sizes, int n_in,
                              void* d_out, int out_size, void* d_ws, size_t ws_size,
                              hipStream_t stream) {
  const float* x1 = (const float*)d_in[0];
  const float* x2 = (const float*)d_in[1];
  float* out = (float*)d_out;
  float* S   = (float*)d_ws;           // B*N*N*4 = 32 MiB

  const int B = in_sizes[0] / (NN * DD);

  ull* gkeys = (ull*)(S + (size_t)B * NN * NN);       // B*CAPS*8 = 2 MiB
  int* gcnt  = (int*)(gkeys + (size_t)B * CAPS);      // B*4
  const int Bev = (B + 1) & ~1;                       // keep 8B alignment
  ull*   gmask  = (ull*)(gcnt + Bev);                 // B*8 ull
  float* gsum   = (float*)(gmask + (size_t)B * 8);    // B*4
  int*   gpicks = (int*)(gsum + B);                   // B*4
  const size_t need = (size_t)((char*)(gpicks + B) - (char*)d_ws);

  dim3 ggrid(NN / 64, NN / 128, B);    // 4 x 2 x 128 = 1024 blocks
  gemm_bt_mfma<<<ggrid, 256, 0, stream>>>(x1, x2, S);

  if (ws_size >= need) {
    collect_sort<<<B, 512, 0, stream>>>(S, gkeys, gcnt);
    scan_match<<<B, 64, 0, stream>>>(gkeys, gcnt, gmask, gsum, gpicks);
    tail_fast<<<B, 256, 0, stream>>>(S, gmask, gsum, gpicks, out);
    tail_safe<<<B, 64, 0, stream>>>(S, gmask, gsum, gpicks, out);
  } else {
    sort_scan_match<<<B, 256, 0, stream>>>(S, out);   // fused fallback
  }
}

// Round 6
// 372.676 us; speedup vs baseline: 1.6461x; 1.6461x over previous
//
#include <hip/hip_runtime.h>
#include <cmath>

// MNEMatch: B pairs of [N,D] fp32; S = x1 @ x2^T per pair; greedy max matching
// (== sort entries desc + scan taking row/col-free entries); out[b]=tanh(sum/N).
#define NN 256
#define DD 384
#define CAPS 2048        // sorted candidate capacity (mean ~1350 at T=40)
#define THRESH 40.0f     // ~2.04 sigma of N(0,384)
#define KCAP 64          // tail fast-path capacity (k mean ~24-40; >64 ~never)
#define RSTRIDE 257      // odd stride: LDS conflicts benign
#define KK2 4096         // tail candidate sort size (KCAP^2)

typedef unsigned long long ull;
typedef short bf16x8 __attribute__((ext_vector_type(8)));
typedef float f32x4  __attribute__((ext_vector_type(4)));

// ---------------- Kernel 1: batched S = A @ B^T via bf16 MFMA --------------
__device__ __forceinline__ unsigned bfpack2(float lo, float hi) {
  return (__float_as_uint(hi) & 0xFFFF0000u) | (__float_as_uint(lo) >> 16);
}

__global__ __launch_bounds__(256) void gemm_bt_mfma(const float* __restrict__ X1,
                                                    const float* __restrict__ X2,
                                                    float* __restrict__ S) {
  const int pair  = blockIdx.z;
  const int rbase = blockIdx.y * 128;
  const int cbase = blockIdx.x * 64;

  __shared__ unsigned short As[128][40];  // 32 k-vals + pad
  __shared__ unsigned short Bs[64][40];

  const int tid   = threadIdx.x;
  const int lane  = tid & 63;
  const int wave  = tid >> 6;
  const int q     = lane >> 4, mi = lane & 15;

  const int srowA = tid >> 1, halfA = tid & 1;
  const int srowB = tid >> 2, qB    = tid & 3;

  const float* Abase = X1 + (size_t)pair * NN * DD + (size_t)(rbase + srowA) * DD + halfA * 16;
  const float* Bbase = X2 + (size_t)pair * NN * DD + (size_t)(cbase + srowB) * DD + qB * 8;

  f32x4 acc[2][4] = {};

  float4 pa0, pa1, pa2, pa3, pb0, pb1;
  {
    const float4* ap = (const float4*)(Abase);
    const float4* bp = (const float4*)(Bbase);
    pa0 = ap[0]; pa1 = ap[1]; pa2 = ap[2]; pa3 = ap[3];
    pb0 = bp[0]; pb1 = bp[1];
  }

  for (int k0 = 0; k0 < DD; k0 += 32) {
    __syncthreads();
    {
      uint4 w0 = make_uint4(bfpack2(pa0.x,pa0.y), bfpack2(pa0.z,pa0.w),
                            bfpack2(pa1.x,pa1.y), bfpack2(pa1.z,pa1.w));
      uint4 w1 = make_uint4(bfpack2(pa2.x,pa2.y), bfpack2(pa2.z,pa2.w),
                            bfpack2(pa3.x,pa3.y), bfpack2(pa3.z,pa3.w));
      *(uint4*)&As[srowA][halfA*16]     = w0;
      *(uint4*)&As[srowA][halfA*16 + 8] = w1;
      uint4 v0 = make_uint4(bfpack2(pb0.x,pb0.y), bfpack2(pb0.z,pb0.w),
                            bfpack2(pb1.x,pb1.y), bfpack2(pb1.z,pb1.w));
      *(uint4*)&Bs[srowB][qB*8] = v0;
    }
    __syncthreads();
    const int kn = k0 + 32;
    if (kn < DD) {
      const float4* ap = (const float4*)(Abase + kn);
      const float4* bp = (const float4*)(Bbase + kn);
      pa0 = ap[0]; pa1 = ap[1]; pa2 = ap[2]; pa3 = ap[3];
      pb0 = bp[0]; pb1 = bp[1];
    }
    bf16x8 af[2], bf[4];
#pragma unroll
    for (int i = 0; i < 2; ++i) af[i] = *(const bf16x8*)&As[wave*32 + i*16 + mi][q*8];
#pragma unroll
    for (int j = 0; j < 4; ++j) bf[j] = *(const bf16x8*)&Bs[j*16 + mi][q*8];
#pragma unroll
    for (int i = 0; i < 2; ++i)
#pragma unroll
      for (int j = 0; j < 4; ++j)
        acc[i][j] = __builtin_amdgcn_mfma_f32_16x16x32_bf16(af[i], bf[j], acc[i][j], 0, 0, 0);
  }

  float* Sp = S + (size_t)pair * NN * NN;
#pragma unroll
  for (int i = 0; i < 2; ++i)
#pragma unroll
    for (int j = 0; j < 4; ++j)
#pragma unroll
      for (int r2 = 0; r2 < 4; ++r2) {
        const int rowg = rbase + wave*32 + i*16 + q*4 + r2;
        const int colg = cbase + j*16 + mi;
        Sp[(size_t)rowg * NN + colg] = acc[i][j][r2];
      }
}

// ---------------- DPP wave64 argmax (result in lane 63) --------------------
#define DPP_STEP(ctrl, rmask)                                                  \
  {                                                                            \
    int vi  = __float_as_int(v);                                               \
    int v2b = __builtin_amdgcn_update_dpp(vi, vi, (ctrl), (rmask), 0xf, false);\
    int i2  = __builtin_amdgcn_update_dpp(c,  c,  (ctrl), (rmask), 0xf, false);\
    float v2 = __int_as_float(v2b);                                            \
    if (v2 > v || (v2 == v && i2 < c)) { v = v2; c = i2; }                     \
  }

__device__ __forceinline__ void dpp_argmax(float& v, int& c) {
  DPP_STEP(0x111, 0xf)  // row_shr:1
  DPP_STEP(0x112, 0xf)  // row_shr:2
  DPP_STEP(0x114, 0xf)  // row_shr:4
  DPP_STEP(0x118, 0xf)  // row_shr:8
  DPP_STEP(0x142, 0xa)  // row_bcast:15
  DPP_STEP(0x143, 0xc)  // row_bcast:31
}
#undef DPP_STEP

__device__ __forceinline__ float rdlane_f(float v, int l) {
  return __int_as_float(__builtin_amdgcn_readlane(__float_as_int(v), l));
}

// masked full-row argmax over alive cols (fused-fallback slow path only)
__device__ __forceinline__ void rescan_row(const float* __restrict__ Sp, int r,
                                           ull a0, ull a1, ull a2, ull a3,
                                           int lane, float& rv, int& rc) {
  float v = -INFINITY; int c = -1;
#pragma unroll
  for (int j = 0; j < 4; ++j) {
    const int cc = j*64 + lane;
    float x = Sp[(size_t)r * NN + cc];
    ull aj = (j==0) ? a0 : (j==1) ? a1 : (j==2) ? a2 : a3;
    float mv = ((aj >> lane) & 1ull) ? x : -INFINITY;
    if (mv > v) { v = mv; c = cc; }
  }
  dpp_argmax(v, c);
  rv = rdlane_f(v, 63);
  rc = __builtin_amdgcn_readlane(c, 63);
}

// i-th set bit (ascending) of a 256-bit mask; 0 if fewer than i+1 bits set
__device__ __forceinline__ int nth_set4(ull m0, ull m1, ull m2, ull m3, int n) {
  int base = 0; ull m = m0;
  int c = __popcll(m);
  if (n >= c) { n -= c; m = m1; base = 64; c = __popcll(m);
    if (n >= c) { n -= c; m = m2; base = 128; c = __popcll(m);
      if (n >= c) { n -= c; m = m3; base = 192; } } }
  for (int i = 0; i < n; ++i) m &= m - 1;
  return m ? (base + (int)__builtin_ctzll(m)) : 0;
}

// max+argmax over one compacted LDS row, cols masked by colAlive (fused fb).
__device__ __forceinline__ void row_max_lds(const float* __restrict__ rowp,
                                            ull colAlive, float& rmv, int& rac) {
  float m0 = -INFINITY, m1 = -INFINITY, m2 = -INFINITY, m3 = -INFINITY;
  int   a0 = 0, a1 = 1, a2 = 2, a3 = 3;
#pragma unroll
  for (int j = 0; j < 64; j += 4) {
    const unsigned g = (unsigned)(colAlive >> j);
    float x0 = (g & 1u) ? rowp[j]     : -INFINITY;
    float x1 = (g & 2u) ? rowp[j + 1] : -INFINITY;
    float x2 = (g & 4u) ? rowp[j + 2] : -INFINITY;
    float x3 = (g & 8u) ? rowp[j + 3] : -INFINITY;
    if (x0 > m0) { m0 = x0; a0 = j; }
    if (x1 > m1) { m1 = x1; a1 = j + 1; }
    if (x2 > m2) { m2 = x2; a2 = j + 2; }
    if (x3 > m3) { m3 = x3; a3 = j + 3; }
  }
  float mv = m0; int ai = a0;
  if (m1 > mv) { mv = m1; ai = a1; }
  if (m2 > mv) { mv = m2; ai = a2; }
  if (m3 > mv) { mv = m3; ai = a3; }
  rmv = mv; rac = ai;
}

// per-lane scan of its OWN row over alive cols (k>KCAP safety path only)
__device__ __forceinline__ void scan_own_row(const float* __restrict__ rowp,
                                             ull a0, ull a1, ull a2, ull a3,
                                             float& mv, int& ac) {
  float v = -INFINITY; int c = 0;
#pragma unroll
  for (int g = 0; g < 4; ++g) {
    const ull am = (g==0) ? a0 : (g==1) ? a1 : (g==2) ? a2 : a3;
#pragma unroll 8
    for (int j = 0; j < 64; ++j) {
      if ((am >> j) & 1ull) {
        const float x = rowp[g*64 + j];
        if (x > v) { v = x; c = g*64 + j; }
      }
    }
  }
  mv = v; ac = c;
}

// ---- legacy tail (fused fallback only): serial gather + global rescans ----
__device__ float finish_tail(const float* __restrict__ Sp, float* __restrict__ sub,
                             int lane,
                             ull arow0, ull arow1, ull arow2, ull arow3,
                             ull acol0, ull acol1, ull acol2, ull acol3,
                             int picks, float sum) {
  if (picks >= NN) return sum;
  const int k = NN - picks;
  if (k <= 64) {
    const int myRow = nth_set4(arow0, arow1, arow2, arow3, lane);
    const int myCol = nth_set4(acol0, acol1, acol2, acol3, lane);
    for (int i = 0; i < k; ++i) {
      const int ri = __builtin_amdgcn_readlane(myRow, i);
      float v = 0.0f;
      if (lane < k) v = Sp[(size_t)ri * NN + myCol];
      sub[i * 65 + lane] = v;
    }
    asm volatile("s_waitcnt lgkmcnt(0)" ::: "memory");
    __builtin_amdgcn_wave_barrier();

    const ull fullMask = (k == 64) ? ~0ull : ((1ull << k) - 1ull);
    ull rowAlive = fullMask, colAlive = fullMask;
    float rmv; int rac;
    row_max_lds(&sub[lane * 65], colAlive, rmv, rac);

    for (int it = 0; it < k; ++it) {
      float v = ((rowAlive >> lane) & 1ull) ? rmv : -INFINITY;
      int c = lane;
      dpp_argmax(v, c);
      const int rstar = __builtin_amdgcn_readlane(c, 63);
      sum += rdlane_f(v, 63);
      const int cstar = __builtin_amdgcn_readlane(rac, rstar);
      rowAlive &= ~(1ull << rstar);
      colAlive &= ~(1ull << cstar);
      const bool stale = ((rowAlive >> lane) & 1ull) && (rac == cstar);
      if (__ballot(stale)) {
        if (stale) row_max_lds(&sub[lane * 65], colAlive, rmv, rac);
      }
    }
  } else {
    float rm[4]; int ra[4];
#pragma unroll
    for (int i = 0; i < 4; ++i) { rm[i] = -INFINITY; ra[i] = -1; }
#pragma unroll
    for (int i = 0; i < 4; ++i) {
      ull m = (i==0) ? arow0 : (i==1) ? arow1 : (i==2) ? arow2 : arow3;
      while (m) {
        const int l = __builtin_ctzll(m); m &= m - 1;
        float rv; int rc;
        rescan_row(Sp, i*64 + l, acol0, acol1, acol2, acol3, lane, rv, rc);
        if (lane == l) { rm[i] = rv; ra[i] = rc; }
      }
    }

    for (int it = picks; it < NN; ++it) {
      float v = rm[0]; int c = lane;
      if (rm[1] > v) { v = rm[1]; c = 64 + lane; }
      if (rm[2] > v) { v = rm[2]; c = 128 + lane; }
      if (rm[3] > v) { v = rm[3]; c = 192 + lane; }
      dpp_argmax(v, c);
      const int   br  = __builtin_amdgcn_readlane(c, 63);
      const float bvv = rdlane_f(v, 63);
      sum += bvv;

      const int bslot = br >> 6, blane = br & 63;
      int myra = ra[0];
      if (bslot == 1) myra = ra[1];
      if (bslot == 2) myra = ra[2];
      if (bslot == 3) myra = ra[3];
      const int bc = __builtin_amdgcn_readlane(myra, blane);

      if (lane == blane) {
        if (bslot == 0) { rm[0] = -INFINITY; ra[0] = -1; }
        if (bslot == 1) { rm[1] = -INFINITY; ra[1] = -1; }
        if (bslot == 2) { rm[2] = -INFINITY; ra[2] = -1; }
        if (bslot == 3) { rm[3] = -INFINITY; ra[3] = -1; }
      }
      const ull cb = ~(1ull << (bc & 63));
      if      (bc < 64)  acol0 &= cb;
      else if (bc < 128) acol1 &= cb;
      else if (bc < 192) acol2 &= cb;
      else               acol3 &= cb;

#pragma unroll
      for (int i = 0; i < 4; ++i) {
        ull m = __ballot(ra[i] == bc);
        while (m) {
          const int l = __builtin_ctzll(m); m &= m - 1;
          float rv; int rc;
          rescan_row(Sp, i*64 + l, acol0, acol1, acol2, acol3, lane, rv, rc);
          if (lane == l) { rm[i] = rv; ra[i] = rc; }
        }
      }
    }
  }
  return sum;
}

// ------ Kernel 2a: collect + bitonic sort (8 waves), keys -> global --------
__global__ __launch_bounds__(512) void collect_sort(const float* __restrict__ S,
                                                    ull* __restrict__ gkeys,
                                                    int* __restrict__ gcnt) {
  const int pair = blockIdx.x;
  const float* Sp = S + (size_t)pair * NN * NN;
  const int tid  = threadIdx.x;
  const int lane = tid & 63;
  const int wv   = tid >> 6;

  __shared__ ull keys[CAPS];           // 16 KB
  __shared__ int lcount;
  if (tid == 0) lcount = 0;
  __syncthreads();

  // ---- collect entries > THRESH ----
  const float4* S4 = (const float4*)Sp;
#pragma unroll 4
  for (int i4 = tid; i4 < NN*NN/4; i4 += 512) {
    float4 x = S4[i4];
    float xv[4] = {x.x, x.y, x.z, x.w};
#pragma unroll
    for (int e = 0; e < 4; ++e) {
      if (xv[e] > THRESH) {
        unsigned b = __float_as_uint(xv[e]);
        unsigned u = (b & 0x80000000u) ? ~b : (b | 0x80000000u);  // monotone asc
        int pos = atomicAdd(&lcount, 1);
        if (pos < CAPS)
          keys[pos] = ((ull)(~u) << 32) | (unsigned)(i4*4 + e);
      }
    }
  }
  __syncthreads();
  int count = lcount;
  if (count > CAPS) count = 0;         // overflow => exact fallback downstream
  for (int i = count + tid; i < CAPS; i += 512) keys[i] = ~0ull;
  __syncthreads();

  // ---- bitonic sort ascending; wave-local 256-elem chunks ----
#define CMPSWAP(I, K)                                                          \
  {                                                                            \
    unsigned ixj = (I) ^ j;                                                    \
    if (ixj > (I)) {                                                           \
      ull a = keys[(I)], b = keys[ixj];                                        \
      bool asc = (((I) & (K)) == 0);                                           \
      if ((a > b) == asc) { keys[(I)] = b; keys[ixj] = a; }                    \
    }                                                                          \
  }

  const unsigned wbase = wv * 256;
  for (unsigned k = 2; k <= 256; k <<= 1)
    for (unsigned j = k >> 1; j > 0; j >>= 1) {
      for (unsigned t = lane; t < 256; t += 64) { unsigned i = wbase + t; CMPSWAP(i, k) }
      __builtin_amdgcn_wave_barrier();
    }
  __syncthreads();
  // k=512: j=256 cross, then local
  { unsigned j = 256; for (unsigned i = tid; i < CAPS; i += 512) CMPSWAP(i, 512) }
  __syncthreads();
  for (unsigned j = 128; j > 0; j >>= 1) {
    for (unsigned t = lane; t < 256; t += 64) { unsigned i = wbase + t; CMPSWAP(i, 512) }
    __builtin_amdgcn_wave_barrier();
  }
  __syncthreads();
  // k=1024: j=512,256 cross, then local
  { unsigned j = 512; for (unsigned i = tid; i < CAPS; i += 512) CMPSWAP(i, 1024) }
  __syncthreads();
  { unsigned j = 256; for (unsigned i = tid; i < CAPS; i += 512) CMPSWAP(i, 1024) }
  __syncthreads();
  for (unsigned j = 128; j > 0; j >>= 1) {
    for (unsigned t = lane; t < 256; t += 64) { unsigned i = wbase + t; CMPSWAP(i, 1024) }
    __builtin_amdgcn_wave_barrier();
  }
  __syncthreads();
  // k=2048: j=1024,512,256 cross, then local
  { unsigned j = 1024; for (unsigned i = tid; i < CAPS; i += 512) CMPSWAP(i, 2048) }
  __syncthreads();
  { unsigned j = 512; for (unsigned i = tid; i < CAPS; i += 512) CMPSWAP(i, 2048) }
  __syncthreads();
  { unsigned j = 256; for (unsigned i = tid; i < CAPS; i += 512) CMPSWAP(i, 2048) }
  __syncthreads();
  for (unsigned j = 128; j > 0; j >>= 1) {
    for (unsigned t = lane; t < 256; t += 64) { unsigned i = wbase + t; CMPSWAP(i, 2048) }
    __builtin_amdgcn_wave_barrier();
  }
#undef CMPSWAP
  __syncthreads();

  for (int i = tid; i < count; i += 512) gkeys[(size_t)pair * CAPS + i] = keys[i];
  if (tid == 0) gcnt[pair] = count;
}

// ------ Kernel 2b: ordered scan (phase 3 only), 1 wave per pair ------------
__global__ __launch_bounds__(64) void scan_match(const ull* __restrict__ gkeys,
                                                 const int* __restrict__ gcnt,
                                                 ull* __restrict__ gmask,
                                                 float* __restrict__ gsum,
                                                 int* __restrict__ gpicks) {
  const int pair = blockIdx.x;
  const int lane = threadIdx.x;
  const int count = gcnt[pair];
  const ull* kp = gkeys + (size_t)pair * CAPS;

  unsigned rowAlive = 0xFu, colAlive = 0xFu;   // 4 rows/cols per lane
  float sum = 0.0f;
  int picks = 0;

  // prefetch first batch
  ull key = ~0ull;
  if (count > 0) { int i0 = (lane < count) ? lane : 0; key = kp[i0]; }

  for (int base = 0; base < count && picks < NN; base += 64) {
    // issue next batch's load before processing current (hides latency)
    ull nkey = ~0ull;
    const int nbase = base + 64;
    if (nbase < count) { int ni = nbase + lane; if (ni >= count) ni = nbase; nkey = kp[ni]; }

    const int flat = (int)(unsigned)key;
    const int r = (flat >> 8) & 255, c = flat & 255;
    const unsigned u = ~(unsigned)(key >> 32);
    const float val = __uint_as_float((u & 0x80000000u) ? (u ^ 0x80000000u) : ~u);
    const bool valid = (base + lane) < count;

    // batch init: fetch alive bits of (r,c) from owning lanes
    const int rbits = __builtin_amdgcn_ds_bpermute((r & 63) << 2, (int)rowAlive);
    const int cbits = __builtin_amdgcn_ds_bpermute((c & 63) << 2, (int)colAlive);
    bool alive = valid && (((rbits >> (r >> 6)) & 1) != 0) && (((cbits >> (c >> 6)) & 1) != 0);

    // per-pick recurrence: ballot -> ctz -> readlane -> compare-kill
    while (true) {
      const ull mb = __ballot(alive);
      if (!mb) break;
      const int t   = __builtin_ctzll(mb);       // lowest lane = sorted order
      const int r_t = __builtin_amdgcn_readlane(r, t);
      const int c_t = __builtin_amdgcn_readlane(c, t);
      sum += rdlane_f(val, t);
      ++picks;
      alive = alive && (r != r_t) && (c != c_t);
      rowAlive &= ~((lane == (r_t & 63) ? 1u : 0u) << (r_t >> 6));
      colAlive &= ~((lane == (c_t & 63) ? 1u : 0u) << (c_t >> 6));
      if (picks == NN) break;
    }
    key = nkey;
  }

  // reconstruct 256-bit masks (8 ballots) and persist state
  ull m[8];
#pragma unroll
  for (int i = 0; i < 4; ++i) m[i]     = __ballot(((rowAlive >> i) & 1u) != 0);
#pragma unroll
  for (int i = 0; i < 4; ++i) m[4 + i] = __ballot(((colAlive >> i) & 1u) != 0);
  if (lane == 0) {
    ull* mp = gmask + (size_t)pair * 8;
#pragma unroll
    for (int i = 0; i < 8; ++i) mp[i] = m[i];
    gsum[pair]   = sum;
    gpicks[pair] = picks;
  }
}

// ------ Kernel 2c: tail via sort+scan (k <= KCAP) --------------------------
// No per-pick rescans: gather alive rows coalesced -> enumerate all k*k alive
// entries -> bitonic sort -> ballot compare-kill scan (phase-3 machinery).
__global__ __launch_bounds__(256) void tail_fast(const float* __restrict__ S,
                                                 const ull* __restrict__ gmask,
                                                 const float* __restrict__ gsum,
                                                 const int* __restrict__ gpicks,
                                                 float* __restrict__ out) {
  const int pair = blockIdx.x;
  const int tid  = threadIdx.x;
  const int lane = tid & 63;
  const int wv   = tid >> 6;
  const float* Sp = S + (size_t)pair * NN * NN;

  __shared__ float rows[KCAP * RSTRIDE];   // 65.8 KB: alive rows, full 256 cols
  __shared__ ull keys2[KK2];               // 32 KB

  float sum = gsum[pair];
  const int picks = gpicks[pair];
  if (picks >= NN) {
    if (tid == 0) out[pair] = tanhf(sum / (float)NN);
    return;
  }
  const int k = NN - picks;
  if (k > KCAP) return;                    // tail_safe handles (rare/never)

  const ull* mp = gmask + (size_t)pair * 8;
  const ull arow0 = mp[0], arow1 = mp[1], arow2 = mp[2], arow3 = mp[3];
  const ull acol0 = mp[4], acol1 = mp[5], acol2 = mp[6], acol3 = mp[7];

  // ---- gather: 4 threads/row, coalesced float4 ----
  const int slot = tid >> 2, seg = tid & 3;
  if (slot < k) {
    const int r = nth_set4(arow0, arow1, arow2, arow3, slot);
    const float4* src = (const float4*)(Sp + (size_t)r * NN + seg * 64);
    float* dst = &rows[slot * RSTRIDE + seg * 64];
#pragma unroll
    for (int i = 0; i < 16; ++i) {
      float4 v = src[i];
      dst[i*4 + 0] = v.x; dst[i*4 + 1] = v.y;
      dst[i*4 + 2] = v.z; dst[i*4 + 3] = v.w;
    }
  }
  const int nkk = k * k;
  for (int i = nkk + tid; i < KK2; i += 256) keys2[i] = ~0ull;  // pad (disjoint)
  __syncthreads();

  // ---- enumerate k*k alive entries; pos = slot*k + colrank (no atomics) ----
  if (slot < k) {
    const int cb0 = __popcll(acol0);
    const int cb1 = cb0 + __popcll(acol1);
    const int cb2 = cb1 + __popcll(acol2);
    int crank = (seg == 0) ? 0 : (seg == 1) ? cb0 : (seg == 2) ? cb1 : cb2;
    const ull aseg = (seg == 0) ? acol0 : (seg == 1) ? acol1 : (seg == 2) ? acol2 : acol3;
    const float* rp = &rows[slot * RSTRIDE + seg * 64];
    for (int j = 0; j < 64; ++j) {
      if ((aseg >> j) & 1ull) {
        const unsigned b = __float_as_uint(rp[j]);
        const unsigned u = (b & 0x80000000u) ? ~b : (b | 0x80000000u);
        keys2[slot * k + crank] = ((ull)(~u) << 32) | (unsigned)((slot << 6) | crank);
        ++crank;
      }
    }
  }
  __syncthreads();

  // ---- bitonic sort 4096 ascending; wave-local 1024-elem chunks ----
#define CMPSWAP2(I, K)                                                         \
  {                                                                            \
    unsigned ixj = (I) ^ j;                                                    \
    if (ixj > (I)) {                                                           \
      ull a = keys2[(I)], b = keys2[ixj];                                      \
      bool asc = (((I) & (K)) == 0);                                           \
      if ((a > b) == asc) { keys2[(I)] = b; keys2[ixj] = a; }                  \
    }                                                                          \
  }
  const unsigned wbase = wv * 1024;
  for (unsigned kk = 2; kk <= 1024; kk <<= 1)
    for (unsigned j = kk >> 1; j > 0; j >>= 1) {
      for (unsigned t = lane; t < 1024; t += 64) { unsigned i = wbase + t; CMPSWAP2(i, kk) }
      __builtin_amdgcn_wave_barrier();
    }
  __syncthreads();
  // kk=2048: j=1024 cross, then local
  { unsigned j = 1024; for (unsigned i = tid; i < KK2; i += 256) CMPSWAP2(i, 2048) }
  __syncthreads();
  for (unsigned j = 512; j > 0; j >>= 1) {
    for (unsigned t = lane; t < 1024; t += 64) { unsigned i = wbase + t; CMPSWAP2(i, 2048) }
    __builtin_amdgcn_wave_barrier();
  }
  __syncthreads();
  // kk=4096: j=2048,1024 cross, then local
  { unsigned j = 2048; for (unsigned i = tid; i < KK2; i += 256) CMPSWAP2(i, 4096) }
  __syncthreads();
  { unsigned j = 1024; for (unsigned i = tid; i < KK2; i += 256) CMPSWAP2(i, 4096) }
  __syncthreads();
  for (unsigned j = 512; j > 0; j >>= 1) {
    for (unsigned t = lane; t < 1024; t += 64) { unsigned i = wbase + t; CMPSWAP2(i, 4096) }
    __builtin_amdgcn_wave_barrier();
  }
#undef CMPSWAP2
  __syncthreads();
  if (wv != 0) return;                     // wave 0 scans alone

  // ---- ballot compare-kill scan over sorted k*k entries ----
  ull rAlive = (k == 64) ? ~0ull : ((1ull << k) - 1ull);
  ull cAlive = rAlive;
  int tpicks = 0;
  for (int base = 0; base < nkk && tpicks < k; base += 64) {
    const ull key = keys2[base + lane];
    const int rc = (int)(unsigned)key & 0xFFF;
    const int rs = (rc >> 6) & 63, cs = rc & 63;
    const unsigned u = ~(unsigned)(key >> 32);
    const float val = __uint_as_float((u & 0x80000000u) ? (u ^ 0x80000000u) : ~u);
    const bool valid = (base + lane) < nkk;

    bool alive = valid && (((rAlive >> rs) & 1ull) != 0) && (((cAlive >> cs) & 1ull) != 0);
    while (true) {
      const ull mb = __ballot(alive);
      if (!mb) break;
      const int t    = __builtin_ctzll(mb);    // lowest lane = sorted order
      const int rs_t = __builtin_amdgcn_readlane(rs, t);
      const int cs_t = __builtin_amdgcn_readlane(cs, t);
      sum += rdlane_f(val, t);
      ++tpicks;
      alive = alive && (rs != rs_t) && (cs != cs_t);
      rAlive &= ~(1ull << rs_t);
      cAlive &= ~(1ull << cs_t);
      if (tpicks == k) break;
    }
  }

  if (lane == 0) out[pair] = tanhf(sum / (float)NN);
}

// ------ Kernel 2d: tail SAFE path (k > KCAP) — full global greedy ----------
// Statistically unreachable (k mean ~24-40). If rocprof shows real time here,
// scan_match is under-picking — investigate.
__global__ __launch_bounds__(64) void tail_safe(const float* __restrict__ S,
                                                const ull* __restrict__ gmask,
                                                const float* __restrict__ gsum,
                                                const int* __restrict__ gpicks,
                                                float* __restrict__ out) {
  const int pair = blockIdx.x;
  const int lane = threadIdx.x;
  const float* Sp = S + (size_t)pair * NN * NN;

  float sum = gsum[pair];
  const int picks = gpicks[pair];
  if (picks >= NN) return;                 // handled by tail_fast
  const int k = NN - picks;
  if (k <= KCAP) return;                   // handled by tail_fast

  const ull* mp = gmask + (size_t)pair * 8;
  const ull arow0 = mp[0], arow1 = mp[1], arow2 = mp[2], arow3 = mp[3];
  ull acol0 = mp[4], acol1 = mp[5], acol2 = mp[6], acol3 = mp[7];

  float rm[4]; int ra[4];
#pragma unroll
  for (int i = 0; i < 4; ++i) { rm[i] = -INFINITY; ra[i] = -1; }
  {
    const bool a0 = ((arow0 >> lane) & 1ull) != 0;
    if (a0) scan_own_row(Sp + (size_t)lane * NN, acol0, acol1, acol2, acol3, rm[0], ra[0]);
    const bool a1 = ((arow1 >> lane) & 1ull) != 0;
    if (a1) scan_own_row(Sp + (size_t)(64 + lane) * NN, acol0, acol1, acol2, acol3, rm[1], ra[1]);
    const bool a2 = ((arow2 >> lane) & 1ull) != 0;
    if (a2) scan_own_row(Sp + (size_t)(128 + lane) * NN, acol0, acol1, acol2, acol3, rm[2], ra[2]);
    const bool a3 = ((arow3 >> lane) & 1ull) != 0;
    if (a3) scan_own_row(Sp + (size_t)(192 + lane) * NN, acol0, acol1, acol2, acol3, rm[3], ra[3]);
  }
  for (int it = picks; it < NN; ++it) {
    float v = rm[0]; int c = lane;
    if (rm[1] > v) { v = rm[1]; c = 64 + lane; }
    if (rm[2] > v) { v = rm[2]; c = 128 + lane; }
    if (rm[3] > v) { v = rm[3]; c = 192 + lane; }
    dpp_argmax(v, c);
    const int br = __builtin_amdgcn_readlane(c, 63);
    sum += rdlane_f(v, 63);

    const int bslot = br >> 6, blane = br & 63;
    int myra = ra[0];
    if (bslot == 1) myra = ra[1];
    if (bslot == 2) myra = ra[2];
    if (bslot == 3) myra = ra[3];
    const int bc = __builtin_amdgcn_readlane(myra, blane);

    if (lane == blane) {
      if (bslot == 0) { rm[0] = -INFINITY; ra[0] = -1; }
      if (bslot == 1) { rm[1] = -INFINITY; ra[1] = -1; }
      if (bslot == 2) { rm[2] = -INFINITY; ra[2] = -1; }
      if (bslot == 3) { rm[3] = -INFINITY; ra[3] = -1; }
    }
    { const ull cb = ~(1ull << (bc & 63));
      if      (bc < 64)  acol0 &= cb;
      else if (bc < 128) acol1 &= cb;
      else if (bc < 192) acol2 &= cb;
      else               acol3 &= cb; }

#pragma unroll
    for (int i = 0; i < 4; ++i) {
      const bool st = (ra[i] == bc);
      if (__ballot(st)) {
        if (st) {
          float nv; int nc;
          scan_own_row(Sp + (size_t)(i*64 + lane) * NN, acol0, acol1, acol2, acol3, nv, nc);
          rm[i] = nv; ra[i] = nc;
        }
      }
    }
  }

  if (lane == 0) out[pair] = tanhf(sum / (float)NN);
}

// ------ Fused fallback (used only if workspace can't fit the keys) ---------
__global__ __launch_bounds__(256) void sort_scan_match(const float* __restrict__ S,
                                                       float* __restrict__ out) {
  const int pair = blockIdx.x;
  const float* Sp = S + (size_t)pair * NN * NN;
  const int tid  = threadIdx.x;
  const int lane = tid & 63;
  const int wv   = tid >> 6;

  __shared__ ull keys[CAPS];
  __shared__ float sub[64 * 65];
  __shared__ int lcount;

  if (tid == 0) lcount = 0;
  __syncthreads();

  const float4* S4 = (const float4*)Sp;
#pragma unroll 4
  for (int i4 = tid; i4 < NN*NN/4; i4 += 256) {
    float4 x = S4[i4];
    float xv[4] = {x.x, x.y, x.z, x.w};
#pragma unroll
    for (int e = 0; e < 4; ++e) {
      if (xv[e] > THRESH) {
        unsigned b = __float_as_uint(xv[e]);
        unsigned u = (b & 0x80000000u) ? ~b : (b | 0x80000000u);
        int pos = atomicAdd(&lcount, 1);
        if (pos < CAPS)
          keys[pos] = ((ull)(~u) << 32) | (unsigned)(i4*4 + e);
      }
    }
  }
  __syncthreads();
  int count = lcount;
  if (count > CAPS) count = 0;
  for (int i = count + tid; i < CAPS; i += 256) keys[i] = ~0ull;
  __syncthreads();

#define CMPSWAP(I, K)                                                          \
  {                                                                            \
    unsigned ixj = (I) ^ j;                                                    \
    if (ixj > (I)) {                                                           \
      ull a = keys[(I)], b = keys[ixj];                                        \
      bool asc = (((I) & (K)) == 0);                                           \
      if ((a > b) == asc) { keys[(I)] = b; keys[ixj] = a; }                    \
    }                                                                          \
  }
  const unsigned wbase = wv * 512;
  for (unsigned k = 2; k <= 512; k <<= 1)
    for (unsigned j = k >> 1; j > 0; j >>= 1) {
      for (unsigned t = lane; t < 512; t += 64) { unsigned i = wbase + t; CMPSWAP(i, k) }
      __builtin_amdgcn_wave_barrier();
    }
  __syncthreads();
  { unsigned j = 512; for (unsigned i = tid; i < CAPS; i += 256) CMPSWAP(i, 1024) }
  __syncthreads();
  for (unsigned j = 256; j > 0; j >>= 1) {
    for (unsigned t = lane; t < 512; t += 64) { unsigned i = wbase + t; CMPSWAP(i, 1024) }
    __builtin_amdgcn_wave_barrier();
  }
  __syncthreads();
  { unsigned j = 1024; for (unsigned i = tid; i < CAPS; i += 256) CMPSWAP(i, 2048) }
  __syncthreads();
  { unsigned j = 512; for (unsigned i = tid; i < CAPS; i += 256) CMPSWAP(i, 2048) }
  __syncthreads();
  for (unsigned j = 256; j > 0; j >>= 1) {
    for (unsigned t = lane; t < 512; t += 64) { unsigned i = wbase + t; CMPSWAP(i, 2048) }
    __builtin_amdgcn_wave_barrier();
  }
  __syncthreads();
#undef CMPSWAP

  if (tid >= 64) return;

  ull arow0 = ~0ull, arow1 = ~0ull, arow2 = ~0ull, arow3 = ~0ull;
  ull acol0 = ~0ull, acol1 = ~0ull, acol2 = ~0ull, acol3 = ~0ull;
  float sum = 0.0f;
  int picks = 0;

  for (int base = 0; base < count && picks < NN; base += 64) {
    const ull key = keys[base + lane];
    const int flat = (int)(unsigned)key;
    const int r = (flat >> 8) & 255, c = flat & 255;
    const unsigned u = ~(unsigned)(key >> 32);
    const float val = __uint_as_float((u & 0x80000000u) ? (u ^ 0x80000000u) : ~u);
    const bool valid = (base + lane) < count;

    const ull rs = (r & 128) ? ((r & 64) ? arow3 : arow2) : ((r & 64) ? arow1 : arow0);
    const ull cs = (c & 128) ? ((c & 64) ? acol3 : acol2) : ((c & 64) ? acol1 : acol0);
    bool alive = valid && (((rs >> (r & 63)) & 1ull) != 0) && (((cs >> (c & 63)) & 1ull) != 0);

    while (true) {
      const ull mb = __ballot(alive);
      if (!mb) break;
      const int t   = __builtin_ctzll(mb);
      const int r_t = __builtin_amdgcn_readlane(r, t);
      const int c_t = __builtin_amdgcn_readlane(c, t);
      sum += rdlane_f(val, t);
      ++picks;
      alive = alive && (r != r_t) && (c != c_t);
      {
        const ull rb = 1ull << (r_t & 63); const int rs6 = r_t >> 6;
        arow0 &= ~((rs6 == 0) ? rb : 0ull);
        arow1 &= ~((rs6 == 1) ? rb : 0ull);
        arow2 &= ~((rs6 == 2) ? rb : 0ull);
        arow3 &= ~((rs6 == 3) ? rb : 0ull);
        const ull cb = 1ull << (c_t & 63); const int cs6 = c_t >> 6;
        acol0 &= ~((cs6 == 0) ? cb : 0ull);
        acol1 &= ~((cs6 == 1) ? cb : 0ull);
        acol2 &= ~((cs6 == 2) ? cb : 0ull);
        acol3 &= ~((cs6 == 3) ? cb : 0ull);
      }
      if (picks == NN) break;
    }
  }

  sum = finish_tail(Sp, sub, lane, arow0, arow1, arow2, arow3,
                    acol0, acol1, acol2, acol3, picks, sum);

  if (lane == 0) out[pair] = tanhf(sum / (float)NN);
}

extern "C" void kernel_launch(void* const* d_in, const int* in_sizes, int n_in,
                              void* d_out, int out_size, void* d_ws, size_t ws_size,
                              hipStream_t stream) {
  const float* x1 = (const float*)d_in[0];
  const float* x2 = (const float*)d_in[1];
  float* out = (float*)d_out;
  float* S   = (float*)d_ws;           // B*N*N*4 = 32 MiB

  const int B = in_sizes[0] / (NN * DD);

  ull* gkeys = (ull*)(S + (size_t)B * NN * NN);       // B*CAPS*8 = 2 MiB
  int* gcnt  = (int*)(gkeys + (size_t)B * CAPS);      // B*4
  const int Bev = (B + 1) & ~1;                       // keep 8B alignment
  ull*   gmask  = (ull*)(gcnt + Bev);                 // B*8 ull
  float* gsum   = (float*)(gmask + (size_t)B * 8);    // B*4
  int*   gpicks = (int*)(gsum + B);                   // B*4
  const size_t need = (size_t)((char*)(gpicks + B) - (char*)d_ws);

  dim3 ggrid(NN / 64, NN / 128, B);    // 4 x 2 x 128 = 1024 blocks
  gemm_bt_mfma<<<ggrid, 256, 0, stream>>>(x1, x2, S);

  if (ws_size >= need) {
    collect_sort<<<B, 512, 0, stream>>>(S, gkeys, gcnt);
    scan_match<<<B, 64, 0, stream>>>(gkeys, gcnt, gmask, gsum, gpicks);
    tail_fast<<<B, 256, 0, stream>>>(S, gmask, gsum, gpicks, out);
    tail_safe<<<B, 64, 0, stream>>>(S, gmask, gsum, gpicks, out);
  } else {
    sort_scan_match<<<B, 256, 0, stream>>>(S, out);   // fused fallback
  }
}

// Round 7
// 296.680 us; speedup vs baseline: 2.0677x; 1.2562x over previous
//
#include <hip/hip_runtime.h>
#include <cmath>

// MNEMatch: B pairs of [N,D] fp32; S = x1 @ x2^T per pair; greedy max matching
// (== sort entries desc + scan taking row/col-free entries); out[b]=tanh(sum/N).
#define NN 256
#define DD 384
#define CAPS 2048        // sorted candidate capacity (mean ~1350 at T=40)
#define THRESH 40.0f     // ~2.04 sigma of N(0,384)
#define KCAP 64          // tail fast-path capacity (k mean ~23, max < 64 measured)
#define RSTRIDE 257      // odd stride: LDS conflicts benign
#define KK2 4096         // tail candidate sort capacity (KCAP^2)

typedef unsigned long long ull;
typedef short bf16x8 __attribute__((ext_vector_type(8)));
typedef float f32x4  __attribute__((ext_vector_type(4)));

// ---------------- Kernel 1: batched S = A @ B^T via bf16 MFMA --------------
__device__ __forceinline__ unsigned bfpack2(float lo, float hi) {
  return (__float_as_uint(hi) & 0xFFFF0000u) | (__float_as_uint(lo) >> 16);
}

__global__ __launch_bounds__(256) void gemm_bt_mfma(const float* __restrict__ X1,
                                                    const float* __restrict__ X2,
                                                    float* __restrict__ S) {
  const int pair  = blockIdx.z;
  const int rbase = blockIdx.y * 128;
  const int cbase = blockIdx.x * 64;

  __shared__ unsigned short As[128][40];  // 32 k-vals + pad
  __shared__ unsigned short Bs[64][40];

  const int tid   = threadIdx.x;
  const int lane  = tid & 63;
  const int wave  = tid >> 6;
  const int q     = lane >> 4, mi = lane & 15;

  const int srowA = tid >> 1, halfA = tid & 1;
  const int srowB = tid >> 2, qB    = tid & 3;

  const float* Abase = X1 + (size_t)pair * NN * DD + (size_t)(rbase + srowA) * DD + halfA * 16;
  const float* Bbase = X2 + (size_t)pair * NN * DD + (size_t)(cbase + srowB) * DD + qB * 8;

  f32x4 acc[2][4] = {};

  float4 pa0, pa1, pa2, pa3, pb0, pb1;
  {
    const float4* ap = (const float4*)(Abase);
    const float4* bp = (const float4*)(Bbase);
    pa0 = ap[0]; pa1 = ap[1]; pa2 = ap[2]; pa3 = ap[3];
    pb0 = bp[0]; pb1 = bp[1];
  }

  for (int k0 = 0; k0 < DD; k0 += 32) {
    __syncthreads();
    {
      uint4 w0 = make_uint4(bfpack2(pa0.x,pa0.y), bfpack2(pa0.z,pa0.w),
                            bfpack2(pa1.x,pa1.y), bfpack2(pa1.z,pa1.w));
      uint4 w1 = make_uint4(bfpack2(pa2.x,pa2.y), bfpack2(pa2.z,pa2.w),
                            bfpack2(pa3.x,pa3.y), bfpack2(pa3.z,pa3.w));
      *(uint4*)&As[srowA][halfA*16]     = w0;
      *(uint4*)&As[srowA][halfA*16 + 8] = w1;
      uint4 v0 = make_uint4(bfpack2(pb0.x,pb0.y), bfpack2(pb0.z,pb0.w),
                            bfpack2(pb1.x,pb1.y), bfpack2(pb1.z,pb1.w));
      *(uint4*)&Bs[srowB][qB*8] = v0;
    }
    __syncthreads();
    const int kn = k0 + 32;
    if (kn < DD) {
      const float4* ap = (const float4*)(Abase + kn);
      const float4* bp = (const float4*)(Bbase + kn);
      pa0 = ap[0]; pa1 = ap[1]; pa2 = ap[2]; pa3 = ap[3];
      pb0 = bp[0]; pb1 = bp[1];
    }
    bf16x8 af[2], bf[4];
#pragma unroll
    for (int i = 0; i < 2; ++i) af[i] = *(const bf16x8*)&As[wave*32 + i*16 + mi][q*8];
#pragma unroll
    for (int j = 0; j < 4; ++j) bf[j] = *(const bf16x8*)&Bs[j*16 + mi][q*8];
#pragma unroll
    for (int i = 0; i < 2; ++i)
#pragma unroll
      for (int j = 0; j < 4; ++j)
        acc[i][j] = __builtin_amdgcn_mfma_f32_16x16x32_bf16(af[i], bf[j], acc[i][j], 0, 0, 0);
  }

  float* Sp = S + (size_t)pair * NN * NN;
#pragma unroll
  for (int i = 0; i < 2; ++i)
#pragma unroll
    for (int j = 0; j < 4; ++j)
#pragma unroll
      for (int r2 = 0; r2 < 4; ++r2) {
        const int rowg = rbase + wave*32 + i*16 + q*4 + r2;
        const int colg = cbase + j*16 + mi;
        Sp[(size_t)rowg * NN + colg] = acc[i][j][r2];
      }
}

// ---------------- DPP wave64 argmax (result in lane 63) --------------------
#define DPP_STEP(ctrl, rmask)                                                  \
  {                                                                            \
    int vi  = __float_as_int(v);                                               \
    int v2b = __builtin_amdgcn_update_dpp(vi, vi, (ctrl), (rmask), 0xf, false);\
    int i2  = __builtin_amdgcn_update_dpp(c,  c,  (ctrl), (rmask), 0xf, false);\
    float v2 = __int_as_float(v2b);                                            \
    if (v2 > v || (v2 == v && i2 < c)) { v = v2; c = i2; }                     \
  }

__device__ __forceinline__ void dpp_argmax(float& v, int& c) {
  DPP_STEP(0x111, 0xf)  // row_shr:1
  DPP_STEP(0x112, 0xf)  // row_shr:2
  DPP_STEP(0x114, 0xf)  // row_shr:4
  DPP_STEP(0x118, 0xf)  // row_shr:8
  DPP_STEP(0x142, 0xa)  // row_bcast:15
  DPP_STEP(0x143, 0xc)  // row_bcast:31
}
#undef DPP_STEP

__device__ __forceinline__ float rdlane_f(float v, int l) {
  return __int_as_float(__builtin_amdgcn_readlane(__float_as_int(v), l));
}

// masked full-row argmax over alive cols (fused-fallback slow path only)
__device__ __forceinline__ void rescan_row(const float* __restrict__ Sp, int r,
                                           ull a0, ull a1, ull a2, ull a3,
                                           int lane, float& rv, int& rc) {
  float v = -INFINITY; int c = -1;
#pragma unroll
  for (int j = 0; j < 4; ++j) {
    const int cc = j*64 + lane;
    float x = Sp[(size_t)r * NN + cc];
    ull aj = (j==0) ? a0 : (j==1) ? a1 : (j==2) ? a2 : a3;
    float mv = ((aj >> lane) & 1ull) ? x : -INFINITY;
    if (mv > v) { v = mv; c = cc; }
  }
  dpp_argmax(v, c);
  rv = rdlane_f(v, 63);
  rc = __builtin_amdgcn_readlane(c, 63);
}

// i-th set bit (ascending) of a 256-bit mask; 0 if fewer than i+1 bits set
__device__ __forceinline__ int nth_set4(ull m0, ull m1, ull m2, ull m3, int n) {
  int base = 0; ull m = m0;
  int c = __popcll(m);
  if (n >= c) { n -= c; m = m1; base = 64; c = __popcll(m);
    if (n >= c) { n -= c; m = m2; base = 128; c = __popcll(m);
      if (n >= c) { n -= c; m = m3; base = 192; } } }
  for (int i = 0; i < n; ++i) m &= m - 1;
  return m ? (base + (int)__builtin_ctzll(m)) : 0;
}

// max+argmax over one compacted LDS row, cols masked by colAlive (fused fb).
__device__ __forceinline__ void row_max_lds(const float* __restrict__ rowp,
                                            ull colAlive, float& rmv, int& rac) {
  float m0 = -INFINITY, m1 = -INFINITY, m2 = -INFINITY, m3 = -INFINITY;
  int   a0 = 0, a1 = 1, a2 = 2, a3 = 3;
#pragma unroll
  for (int j = 0; j < 64; j += 4) {
    const unsigned g = (unsigned)(colAlive >> j);
    float x0 = (g & 1u) ? rowp[j]     : -INFINITY;
    float x1 = (g & 2u) ? rowp[j + 1] : -INFINITY;
    float x2 = (g & 4u) ? rowp[j + 2] : -INFINITY;
    float x3 = (g & 8u) ? rowp[j + 3] : -INFINITY;
    if (x0 > m0) { m0 = x0; a0 = j; }
    if (x1 > m1) { m1 = x1; a1 = j + 1; }
    if (x2 > m2) { m2 = x2; a2 = j + 2; }
    if (x3 > m3) { m3 = x3; a3 = j + 3; }
  }
  float mv = m0; int ai = a0;
  if (m1 > mv) { mv = m1; ai = a1; }
  if (m2 > mv) { mv = m2; ai = a2; }
  if (m3 > mv) { mv = m3; ai = a3; }
  rmv = mv; rac = ai;
}

// per-lane scan of its OWN row over alive cols (k>KCAP safety path only)
__device__ __forceinline__ void scan_own_row(const float* __restrict__ rowp,
                                             ull a0, ull a1, ull a2, ull a3,
                                             float& mv, int& ac) {
  float v = -INFINITY; int c = 0;
#pragma unroll
  for (int g = 0; g < 4; ++g) {
    const ull am = (g==0) ? a0 : (g==1) ? a1 : (g==2) ? a2 : a3;
#pragma unroll 8
    for (int j = 0; j < 64; ++j) {
      if ((am >> j) & 1ull) {
        const float x = rowp[g*64 + j];
        if (x > v) { v = x; c = g*64 + j; }
      }
    }
  }
  mv = v; ac = c;
}

// ---- legacy tail (fused fallback only): serial gather + global rescans ----
__device__ float finish_tail(const float* __restrict__ Sp, float* __restrict__ sub,
                             int lane,
                             ull arow0, ull arow1, ull arow2, ull arow3,
                             ull acol0, ull acol1, ull acol2, ull acol3,
                             int picks, float sum) {
  if (picks >= NN) return sum;
  const int k = NN - picks;
  if (k <= 64) {
    const int myRow = nth_set4(arow0, arow1, arow2, arow3, lane);
    const int myCol = nth_set4(acol0, acol1, acol2, acol3, lane);
    for (int i = 0; i < k; ++i) {
      const int ri = __builtin_amdgcn_readlane(myRow, i);
      float v = 0.0f;
      if (lane < k) v = Sp[(size_t)ri * NN + myCol];
      sub[i * 65 + lane] = v;
    }
    asm volatile("s_waitcnt lgkmcnt(0)" ::: "memory");
    __builtin_amdgcn_wave_barrier();

    const ull fullMask = (k == 64) ? ~0ull : ((1ull << k) - 1ull);
    ull rowAlive = fullMask, colAlive = fullMask;
    float rmv; int rac;
    row_max_lds(&sub[lane * 65], colAlive, rmv, rac);

    for (int it = 0; it < k; ++it) {
      float v = ((rowAlive >> lane) & 1ull) ? rmv : -INFINITY;
      int c = lane;
      dpp_argmax(v, c);
      const int rstar = __builtin_amdgcn_readlane(c, 63);
      sum += rdlane_f(v, 63);
      const int cstar = __builtin_amdgcn_readlane(rac, rstar);
      rowAlive &= ~(1ull << rstar);
      colAlive &= ~(1ull << cstar);
      const bool stale = ((rowAlive >> lane) & 1ull) && (rac == cstar);
      if (__ballot(stale)) {
        if (stale) row_max_lds(&sub[lane * 65], colAlive, rmv, rac);
      }
    }
  } else {
    float rm[4]; int ra[4];
#pragma unroll
    for (int i = 0; i < 4; ++i) { rm[i] = -INFINITY; ra[i] = -1; }
#pragma unroll
    for (int i = 0; i < 4; ++i) {
      ull m = (i==0) ? arow0 : (i==1) ? arow1 : (i==2) ? arow2 : arow3;
      while (m) {
        const int l = __builtin_ctzll(m); m &= m - 1;
        float rv; int rc;
        rescan_row(Sp, i*64 + l, acol0, acol1, acol2, acol3, lane, rv, rc);
        if (lane == l) { rm[i] = rv; ra[i] = rc; }
      }
    }

    for (int it = picks; it < NN; ++it) {
      float v = rm[0]; int c = lane;
      if (rm[1] > v) { v = rm[1]; c = 64 + lane; }
      if (rm[2] > v) { v = rm[2]; c = 128 + lane; }
      if (rm[3] > v) { v = rm[3]; c = 192 + lane; }
      dpp_argmax(v, c);
      const int   br  = __builtin_amdgcn_readlane(c, 63);
      const float bvv = rdlane_f(v, 63);
      sum += bvv;

      const int bslot = br >> 6, blane = br & 63;
      int myra = ra[0];
      if (bslot == 1) myra = ra[1];
      if (bslot == 2) myra = ra[2];
      if (bslot == 3) myra = ra[3];
      const int bc = __builtin_amdgcn_readlane(myra, blane);

      if (lane == blane) {
        if (bslot == 0) { rm[0] = -INFINITY; ra[0] = -1; }
        if (bslot == 1) { rm[1] = -INFINITY; ra[1] = -1; }
        if (bslot == 2) { rm[2] = -INFINITY; ra[2] = -1; }
        if (bslot == 3) { rm[3] = -INFINITY; ra[3] = -1; }
      }
      const ull cb = ~(1ull << (bc & 63));
      if      (bc < 64)  acol0 &= cb;
      else if (bc < 128) acol1 &= cb;
      else if (bc < 192) acol2 &= cb;
      else               acol3 &= cb;

#pragma unroll
      for (int i = 0; i < 4; ++i) {
        ull m = __ballot(ra[i] == bc);
        while (m) {
          const int l = __builtin_ctzll(m); m &= m - 1;
          float rv; int rc;
          rescan_row(Sp, i*64 + l, acol0, acol1, acol2, acol3, lane, rv, rc);
          if (lane == l) { rm[i] = rv; ra[i] = rc; }
        }
      }
    }
  }
  return sum;
}

// ------ Kernel 2a: collect + bitonic sort (8 waves), keys -> global --------
__global__ __launch_bounds__(512) void collect_sort(const float* __restrict__ S,
                                                    ull* __restrict__ gkeys,
                                                    int* __restrict__ gcnt) {
  const int pair = blockIdx.x;
  const float* Sp = S + (size_t)pair * NN * NN;
  const int tid  = threadIdx.x;
  const int lane = tid & 63;
  const int wv   = tid >> 6;

  __shared__ ull keys[CAPS];           // 16 KB
  __shared__ int lcount;
  if (tid == 0) lcount = 0;
  __syncthreads();

  // ---- collect entries > THRESH ----
  const float4* S4 = (const float4*)Sp;
#pragma unroll 4
  for (int i4 = tid; i4 < NN*NN/4; i4 += 512) {
    float4 x = S4[i4];
    float xv[4] = {x.x, x.y, x.z, x.w};
#pragma unroll
    for (int e = 0; e < 4; ++e) {
      if (xv[e] > THRESH) {
        unsigned b = __float_as_uint(xv[e]);
        unsigned u = (b & 0x80000000u) ? ~b : (b | 0x80000000u);  // monotone asc
        int pos = atomicAdd(&lcount, 1);
        if (pos < CAPS)
          keys[pos] = ((ull)(~u) << 32) | (unsigned)(i4*4 + e);
      }
    }
  }
  __syncthreads();
  int count = lcount;
  if (count > CAPS) count = 0;         // overflow => exact fallback downstream
  for (int i = count + tid; i < CAPS; i += 512) keys[i] = ~0ull;
  __syncthreads();

  // ---- bitonic sort ascending; wave-local 256-elem chunks ----
#define CMPSWAP(I, K)                                                          \
  {                                                                            \
    unsigned ixj = (I) ^ j;                                                    \
    if (ixj > (I)) {                                                           \
      ull a = keys[(I)], b = keys[ixj];                                        \
      bool asc = (((I) & (K)) == 0);                                           \
      if ((a > b) == asc) { keys[(I)] = b; keys[ixj] = a; }                    \
    }                                                                          \
  }

  const unsigned wbase = wv * 256;
  for (unsigned k = 2; k <= 256; k <<= 1)
    for (unsigned j = k >> 1; j > 0; j >>= 1) {
      for (unsigned t = lane; t < 256; t += 64) { unsigned i = wbase + t; CMPSWAP(i, k) }
      __builtin_amdgcn_wave_barrier();
    }
  __syncthreads();
  // k=512: j=256 cross, then local
  { unsigned j = 256; for (unsigned i = tid; i < CAPS; i += 512) CMPSWAP(i, 512) }
  __syncthreads();
  for (unsigned j = 128; j > 0; j >>= 1) {
    for (unsigned t = lane; t < 256; t += 64) { unsigned i = wbase + t; CMPSWAP(i, 512) }
    __builtin_amdgcn_wave_barrier();
  }
  __syncthreads();
  // k=1024: j=512,256 cross, then local
  { unsigned j = 512; for (unsigned i = tid; i < CAPS; i += 512) CMPSWAP(i, 1024) }
  __syncthreads();
  { unsigned j = 256; for (unsigned i = tid; i < CAPS; i += 512) CMPSWAP(i, 1024) }
  __syncthreads();
  for (unsigned j = 128; j > 0; j >>= 1) {
    for (unsigned t = lane; t < 256; t += 64) { unsigned i = wbase + t; CMPSWAP(i, 1024) }
    __builtin_amdgcn_wave_barrier();
  }
  __syncthreads();
  // k=2048: j=1024,512,256 cross, then local
  { unsigned j = 1024; for (unsigned i = tid; i < CAPS; i += 512) CMPSWAP(i, 2048) }
  __syncthreads();
  { unsigned j = 512; for (unsigned i = tid; i < CAPS; i += 512) CMPSWAP(i, 2048) }
  __syncthreads();
  { unsigned j = 256; for (unsigned i = tid; i < CAPS; i += 512) CMPSWAP(i, 2048) }
  __syncthreads();
  for (unsigned j = 128; j > 0; j >>= 1) {
    for (unsigned t = lane; t < 256; t += 64) { unsigned i = wbase + t; CMPSWAP(i, 2048) }
    __builtin_amdgcn_wave_barrier();
  }
#undef CMPSWAP
  __syncthreads();

  for (int i = tid; i < count; i += 512) gkeys[(size_t)pair * CAPS + i] = keys[i];
  if (tid == 0) gcnt[pair] = count;
}

// ------ Kernel 2b: ordered scan (phase 3 only), 1 wave per pair ------------
__global__ __launch_bounds__(64) void scan_match(const ull* __restrict__ gkeys,
                                                 const int* __restrict__ gcnt,
                                                 ull* __restrict__ gmask,
                                                 float* __restrict__ gsum,
                                                 int* __restrict__ gpicks) {
  const int pair = blockIdx.x;
  const int lane = threadIdx.x;
  const int count = gcnt[pair];
  const ull* kp = gkeys + (size_t)pair * CAPS;

  unsigned rowAlive = 0xFu, colAlive = 0xFu;   // 4 rows/cols per lane
  float sum = 0.0f;
  int picks = 0;

  // prefetch first batch
  ull key = ~0ull;
  if (count > 0) { int i0 = (lane < count) ? lane : 0; key = kp[i0]; }

  for (int base = 0; base < count && picks < NN; base += 64) {
    // issue next batch's load before processing current (hides latency)
    ull nkey = ~0ull;
    const int nbase = base + 64;
    if (nbase < count) { int ni = nbase + lane; if (ni >= count) ni = nbase; nkey = kp[ni]; }

    const int flat = (int)(unsigned)key;
    const int r = (flat >> 8) & 255, c = flat & 255;
    const unsigned u = ~(unsigned)(key >> 32);
    const float val = __uint_as_float((u & 0x80000000u) ? (u ^ 0x80000000u) : ~u);
    const bool valid = (base + lane) < count;

    // batch init: fetch alive bits of (r,c) from owning lanes
    const int rbits = __builtin_amdgcn_ds_bpermute((r & 63) << 2, (int)rowAlive);
    const int cbits = __builtin_amdgcn_ds_bpermute((c & 63) << 2, (int)colAlive);
    bool alive = valid && (((rbits >> (r >> 6)) & 1) != 0) && (((cbits >> (c >> 6)) & 1) != 0);

    // per-pick recurrence: ballot -> ctz -> readlane -> compare-kill
    while (true) {
      const ull mb = __ballot(alive);
      if (!mb) break;
      const int t   = __builtin_ctzll(mb);       // lowest lane = sorted order
      const int r_t = __builtin_amdgcn_readlane(r, t);
      const int c_t = __builtin_amdgcn_readlane(c, t);
      sum += rdlane_f(val, t);
      ++picks;
      alive = alive && (r != r_t) && (c != c_t);
      rowAlive &= ~((lane == (r_t & 63) ? 1u : 0u) << (r_t >> 6));
      colAlive &= ~((lane == (c_t & 63) ? 1u : 0u) << (c_t >> 6));
      if (picks == NN) break;
    }
    key = nkey;
  }

  // reconstruct 256-bit masks (8 ballots) and persist state
  ull m[8];
#pragma unroll
  for (int i = 0; i < 4; ++i) m[i]     = __ballot(((rowAlive >> i) & 1u) != 0);
#pragma unroll
  for (int i = 0; i < 4; ++i) m[4 + i] = __ballot(((colAlive >> i) & 1u) != 0);
  if (lane == 0) {
    ull* mp = gmask + (size_t)pair * 8;
#pragma unroll
    for (int i = 0; i < 8; ++i) mp[i] = m[i];
    gsum[pair]   = sum;
    gpicks[pair] = picks;
  }
}

// ------ Kernel 2c: tail via sort+scan (k <= KCAP), 16 waves ----------------
// No per-pick rescans: gather alive rows coalesced -> enumerate all k*k alive
// entries -> runtime-sized all-block bitonic -> ballot compare-kill scan.
__global__ __launch_bounds__(1024) void tail_fast(const float* __restrict__ S,
                                                  const ull* __restrict__ gmask,
                                                  const float* __restrict__ gsum,
                                                  const int* __restrict__ gpicks,
                                                  float* __restrict__ out) {
  const int pair = blockIdx.x;
  const int tid  = threadIdx.x;
  const int lane = tid & 63;
  const int wv   = tid >> 6;
  const float* Sp = S + (size_t)pair * NN * NN;

  __shared__ float rows[KCAP * RSTRIDE];   // 65.8 KB: alive rows, full 256 cols
  __shared__ ull keys2[KK2];               // 32 KB

  float sum = gsum[pair];
  const int picks = gpicks[pair];
  if (picks >= NN) {
    if (tid == 0) out[pair] = tanhf(sum / (float)NN);
    return;
  }
  const int k = NN - picks;
  if (k > KCAP) return;                    // tail_safe handles (never observed)

  const ull* mp = gmask + (size_t)pair * 8;
  const ull arow0 = mp[0], arow1 = mp[1], arow2 = mp[2], arow3 = mp[3];
  const ull acol0 = mp[4], acol1 = mp[5], acol2 = mp[6], acol3 = mp[7];

  // ---- gather: 16 threads/row, coalesced float4 (1KB/row) ----
  const int slot = tid >> 4;               // 0..63 alive-row slot
  const int seg  = tid & 15;               // 16-col group within the row
  if (slot < k) {
    const int r = nth_set4(arow0, arow1, arow2, arow3, slot);
    const float4* src = (const float4*)(Sp + (size_t)r * NN + seg * 16);
    float* dst = &rows[slot * RSTRIDE + seg * 16];
#pragma unroll
    for (int i = 0; i < 4; ++i) {
      float4 v = src[i];
      dst[i*4 + 0] = v.x; dst[i*4 + 1] = v.y;
      dst[i*4 + 2] = v.z; dst[i*4 + 3] = v.w;
    }
  }
  const int nkk = k * k;
  int n2 = 64; while (n2 < nkk) n2 <<= 1;  // runtime sort size (<= 4096)
  for (int i = nkk + tid; i < n2; i += 1024) keys2[i] = ~0ull;  // pad
  __syncthreads();

  // ---- enumerate k*k alive entries; pos = slot*k + colrank (no atomics) ----
  if (slot < k) {
    const int w  = seg >> 2;               // acol word of this 16-col group
    const int sb = (seg & 3) * 16;         // start bit within the word
    const ull aw = (w==0) ? acol0 : (w==1) ? acol1 : (w==2) ? acol2 : acol3;
    int crank = 0;
    if (w > 0) crank += __popcll(acol0);
    if (w > 1) crank += __popcll(acol1);
    if (w > 2) crank += __popcll(acol2);
    crank += __popcll(aw & ((1ull << sb) - 1ull));
    const float* rp = &rows[slot * RSTRIDE + w * 64];
    for (int j = sb; j < sb + 16; ++j) {
      if ((aw >> j) & 1ull) {
        const unsigned b = __float_as_uint(rp[j]);
        const unsigned u = (b & 0x80000000u) ? ~b : (b | 0x80000000u);
        keys2[slot * k + crank] = ((ull)(~u) << 32) | (unsigned)((slot << 6) | crank);
        ++crank;
      }
    }
  }
  __syncthreads();

  // ---- all-block bitonic sort (runtime n2), 16 waves, barrier per step ----
  for (unsigned kk = 2; kk <= (unsigned)n2; kk <<= 1)
    for (unsigned j = kk >> 1; j > 0; j >>= 1) {
      for (unsigned i = tid; i < (unsigned)n2; i += 1024) {
        unsigned ixj = i ^ j;
        if (ixj > i) {
          ull a = keys2[i], b = keys2[ixj];
          bool asc = ((i & kk) == 0);
          if ((a > b) == asc) { keys2[i] = b; keys2[ixj] = a; }
        }
      }
      __syncthreads();
    }
  if (wv != 0) return;                     // wave 0 scans alone

  // ---- ballot compare-kill scan over sorted k*k entries ----
  ull rAlive = (k == 64) ? ~0ull : ((1ull << k) - 1ull);
  ull cAlive = rAlive;
  int tpicks = 0;
  for (int base = 0; base < nkk && tpicks < k; base += 64) {
    const ull key = keys2[base + lane];
    const int rc = (int)(unsigned)key & 0xFFF;
    const int rs = (rc >> 6) & 63, cs = rc & 63;
    const unsigned u = ~(unsigned)(key >> 32);
    const float val = __uint_as_float((u & 0x80000000u) ? (u ^ 0x80000000u) : ~u);
    const bool valid = (base + lane) < nkk;

    bool alive = valid && (((rAlive >> rs) & 1ull) != 0) && (((cAlive >> cs) & 1ull) != 0);
    while (true) {
      const ull mb = __ballot(alive);
      if (!mb) break;
      const int t    = __builtin_ctzll(mb);    // lowest lane = sorted order
      const int rs_t = __builtin_amdgcn_readlane(rs, t);
      const int cs_t = __builtin_amdgcn_readlane(cs, t);
      sum += rdlane_f(val, t);
      ++tpicks;
      alive = alive && (rs != rs_t) && (cs != cs_t);
      rAlive &= ~(1ull << rs_t);
      cAlive &= ~(1ull << cs_t);
      if (tpicks == k) break;
    }
  }

  if (lane == 0) out[pair] = tanhf(sum / (float)NN);
}

// ------ Kernel 2d: tail SAFE path (k > KCAP) — full global greedy ----------
// Never observed (no pair has k > 64 under T=40). Correctness net only.
__global__ __launch_bounds__(64) void tail_safe(const float* __restrict__ S,
                                                const ull* __restrict__ gmask,
                                                const float* __restrict__ gsum,
                                                const int* __restrict__ gpicks,
                                                float* __restrict__ out) {
  const int pair = blockIdx.x;
  const int lane = threadIdx.x;
  const float* Sp = S + (size_t)pair * NN * NN;

  float sum = gsum[pair];
  const int picks = gpicks[pair];
  if (picks >= NN) return;                 // handled by tail_fast
  const int k = NN - picks;
  if (k <= KCAP) return;                   // handled by tail_fast

  const ull* mp = gmask + (size_t)pair * 8;
  const ull arow0 = mp[0], arow1 = mp[1], arow2 = mp[2], arow3 = mp[3];
  ull acol0 = mp[4], acol1 = mp[5], acol2 = mp[6], acol3 = mp[7];

  float rm[4]; int ra[4];
#pragma unroll
  for (int i = 0; i < 4; ++i) { rm[i] = -INFINITY; ra[i] = -1; }
  {
    const bool a0 = ((arow0 >> lane) & 1ull) != 0;
    if (a0) scan_own_row(Sp + (size_t)lane * NN, acol0, acol1, acol2, acol3, rm[0], ra[0]);
    const bool a1 = ((arow1 >> lane) & 1ull) != 0;
    if (a1) scan_own_row(Sp + (size_t)(64 + lane) * NN, acol0, acol1, acol2, acol3, rm[1], ra[1]);
    const bool a2 = ((arow2 >> lane) & 1ull) != 0;
    if (a2) scan_own_row(Sp + (size_t)(128 + lane) * NN, acol0, acol1, acol2, acol3, rm[2], ra[2]);
    const bool a3 = ((arow3 >> lane) & 1ull) != 0;
    if (a3) scan_own_row(Sp + (size_t)(192 + lane) * NN, acol0, acol1, acol2, acol3, rm[3], ra[3]);
  }
  for (int it = picks; it < NN; ++it) {
    float v = rm[0]; int c = lane;
    if (rm[1] > v) { v = rm[1]; c = 64 + lane; }
    if (rm[2] > v) { v = rm[2]; c = 128 + lane; }
    if (rm[3] > v) { v = rm[3]; c = 192 + lane; }
    dpp_argmax(v, c);
    const int br = __builtin_amdgcn_readlane(c, 63);
    sum += rdlane_f(v, 63);

    const int bslot = br >> 6, blane = br & 63;
    int myra = ra[0];
    if (bslot == 1) myra = ra[1];
    if (bslot == 2) myra = ra[2];
    if (bslot == 3) myra = ra[3];
    const int bc = __builtin_amdgcn_readlane(myra, blane);

    if (lane == blane) {
      if (bslot == 0) { rm[0] = -INFINITY; ra[0] = -1; }
      if (bslot == 1) { rm[1] = -INFINITY; ra[1] = -1; }
      if (bslot == 2) { rm[2] = -INFINITY; ra[2] = -1; }
      if (bslot == 3) { rm[3] = -INFINITY; ra[3] = -1; }
    }
    { const ull cb = ~(1ull << (bc & 63));
      if      (bc < 64)  acol0 &= cb;
      else if (bc < 128) acol1 &= cb;
      else if (bc < 192) acol2 &= cb;
      else               acol3 &= cb; }

#pragma unroll
    for (int i = 0; i < 4; ++i) {
      const bool st = (ra[i] == bc);
      if (__ballot(st)) {
        if (st) {
          float nv; int nc;
          scan_own_row(Sp + (size_t)(i*64 + lane) * NN, acol0, acol1, acol2, acol3, nv, nc);
          rm[i] = nv; ra[i] = nc;
        }
      }
    }
  }

  if (lane == 0) out[pair] = tanhf(sum / (float)NN);
}

// ------ Fused fallback (used only if workspace can't fit the keys) ---------
__global__ __launch_bounds__(256) void sort_scan_match(const float* __restrict__ S,
                                                       float* __restrict__ out) {
  const int pair = blockIdx.x;
  const float* Sp = S + (size_t)pair * NN * NN;
  const int tid  = threadIdx.x;
  const int lane = tid & 63;
  const int wv   = tid >> 6;

  __shared__ ull keys[CAPS];
  __shared__ float sub[64 * 65];
  __shared__ int lcount;

  if (tid == 0) lcount = 0;
  __syncthreads();

  const float4* S4 = (const float4*)Sp;
#pragma unroll 4
  for (int i4 = tid; i4 < NN*NN/4; i4 += 256) {
    float4 x = S4[i4];
    float xv[4] = {x.x, x.y, x.z, x.w};
#pragma unroll
    for (int e = 0; e < 4; ++e) {
      if (xv[e] > THRESH) {
        unsigned b = __float_as_uint(xv[e]);
        unsigned u = (b & 0x80000000u) ? ~b : (b | 0x80000000u);
        int pos = atomicAdd(&lcount, 1);
        if (pos < CAPS)
          keys[pos] = ((ull)(~u) << 32) | (unsigned)(i4*4 + e);
      }
    }
  }
  __syncthreads();
  int count = lcount;
  if (count > CAPS) count = 0;
  for (int i = count + tid; i < CAPS; i += 256) keys[i] = ~0ull;
  __syncthreads();

#define CMPSWAP(I, K)                                                          \
  {                                                                            \
    unsigned ixj = (I) ^ j;                                                    \
    if (ixj > (I)) {                                                           \
      ull a = keys[(I)], b = keys[ixj];                                        \
      bool asc = (((I) & (K)) == 0);                                           \
      if ((a > b) == asc) { keys[(I)] = b; keys[ixj] = a; }                    \
    }                                                                          \
  }
  const unsigned wbase = wv * 512;
  for (unsigned k = 2; k <= 512; k <<= 1)
    for (unsigned j = k >> 1; j > 0; j >>= 1) {
      for (unsigned t = lane; t < 512; t += 64) { unsigned i = wbase + t; CMPSWAP(i, k) }
      __builtin_amdgcn_wave_barrier();
    }
  __syncthreads();
  { unsigned j = 512; for (unsigned i = tid; i < CAPS; i += 256) CMPSWAP(i, 1024) }
  __syncthreads();
  for (unsigned j = 256; j > 0; j >>= 1) {
    for (unsigned t = lane; t < 512; t += 64) { unsigned i = wbase + t; CMPSWAP(i, 1024) }
    __builtin_amdgcn_wave_barrier();
  }
  __syncthreads();
  { unsigned j = 1024; for (unsigned i = tid; i < CAPS; i += 256) CMPSWAP(i, 2048) }
  __syncthreads();
  { unsigned j = 512; for (unsigned i = tid; i < CAPS; i += 256) CMPSWAP(i, 2048) }
  __syncthreads();
  for (unsigned j = 256; j > 0; j >>= 1) {
    for (unsigned t = lane; t < 512; t += 64) { unsigned i = wbase + t; CMPSWAP(i, 2048) }
    __builtin_amdgcn_wave_barrier();
  }
  __syncthreads();
#undef CMPSWAP

  if (tid >= 64) return;

  ull arow0 = ~0ull, arow1 = ~0ull, arow2 = ~0ull, arow3 = ~0ull;
  ull acol0 = ~0ull, acol1 = ~0ull, acol2 = ~0ull, acol3 = ~0ull;
  float sum = 0.0f;
  int picks = 0;

  for (int base = 0; base < count && picks < NN; base += 64) {
    const ull key = keys[base + lane];
    const int flat = (int)(unsigned)key;
    const int r = (flat >> 8) & 255, c = flat & 255;
    const unsigned u = ~(unsigned)(key >> 32);
    const float val = __uint_as_float((u & 0x80000000u) ? (u ^ 0x80000000u) : ~u);
    const bool valid = (base + lane) < count;

    const ull rs = (r & 128) ? ((r & 64) ? arow3 : arow2) : ((r & 64) ? arow1 : arow0);
    const ull cs = (c & 128) ? ((c & 64) ? acol3 : acol2) : ((c & 64) ? acol1 : acol0);
    bool alive = valid && (((rs >> (r & 63)) & 1ull) != 0) && (((cs >> (c & 63)) & 1ull) != 0);

    while (true) {
      const ull mb = __ballot(alive);
      if (!mb) break;
      const int t   = __builtin_ctzll(mb);
      const int r_t = __builtin_amdgcn_readlane(r, t);
      const int c_t = __builtin_amdgcn_readlane(c, t);
      sum += rdlane_f(val, t);
      ++picks;
      alive = alive && (r != r_t) && (c != c_t);
      {
        const ull rb = 1ull << (r_t & 63); const int rs6 = r_t >> 6;
        arow0 &= ~((rs6 == 0) ? rb : 0ull);
        arow1 &= ~((rs6 == 1) ? rb : 0ull);
        arow2 &= ~((rs6 == 2) ? rb : 0ull);
        arow3 &= ~((rs6 == 3) ? rb : 0ull);
        const ull cb = 1ull << (c_t & 63); const int cs6 = c_t >> 6;
        acol0 &= ~((cs6 == 0) ? cb : 0ull);
        acol1 &= ~((cs6 == 1) ? cb : 0ull);
        acol2 &= ~((cs6 == 2) ? cb : 0ull);
        acol3 &= ~((cs6 == 3) ? cb : 0ull);
      }
      if (picks == NN) break;
    }
  }

  sum = finish_tail(Sp, sub, lane, arow0, arow1, arow2, arow3,
                    acol0, acol1, acol2, acol3, picks, sum);

  if (lane == 0) out[pair] = tanhf(sum / (float)NN);
}

extern "C" void kernel_launch(void* const* d_in, const int* in_sizes, int n_in,
                              void* d_out, int out_size, void* d_ws, size_t ws_size,
                              hipStream_t stream) {
  const float* x1 = (const float*)d_in[0];
  const float* x2 = (const float*)d_in[1];
  float* out = (float*)d_out;
  float* S   = (float*)d_ws;           // B*N*N*4 = 32 MiB

  const int B = in_sizes[0] / (NN * DD);

  ull* gkeys = (ull*)(S + (size_t)B * NN * NN);       // B*CAPS*8 = 2 MiB
  int* gcnt  = (int*)(gkeys + (size_t)B * CAPS);      // B*4
  const int Bev = (B + 1) & ~1;                       // keep 8B alignment
  ull*   gmask  = (ull*)(gcnt + Bev);                 // B*8 ull
  float* gsum   = (float*)(gmask + (size_t)B * 8);    // B*4
  int*   gpicks = (int*)(gsum + B);                   // B*4
  const size_t need = (size_t)((char*)(gpicks + B) - (char*)d_ws);

  dim3 ggrid(NN / 64, NN / 128, B);    // 4 x 2 x 128 = 1024 blocks
  gemm_bt_mfma<<<ggrid, 256, 0, stream>>>(x1, x2, S);

  if (ws_size >= need) {
    collect_sort<<<B, 512, 0, stream>>>(S, gkeys, gcnt);
    scan_match<<<B, 64, 0, stream>>>(gkeys, gcnt, gmask, gsum, gpicks);
    tail_fast<<<B, 1024, 0, stream>>>(S, gmask, gsum, gpicks, out);
    tail_safe<<<B, 64, 0, stream>>>(S, gmask, gsum, gpicks, out);
  } else {
    sort_scan_match<<<B, 256, 0, stream>>>(S, out);   // fused fallback
  }
}

// Round 8
// 270.900 us; speedup vs baseline: 2.2645x; 1.0952x over previous
//
#include <hip/hip_runtime.h>
#include <cmath>

// MNEMatch: B pairs of [N,D] fp32; S = x1 @ x2^T per pair; greedy max matching
// (== sort entries desc + scan taking row/col-free entries); out[b]=tanh(sum/N).
#define NN 256
#define DD 384
#define CAPS 2048        // sorted candidate capacity (mean ~1350 at T=40)
#define THRESH 40.0f     // ~2.04 sigma of N(0,384)
#define KCAP 64          // tail fast-path capacity (k mean ~23, max < 64 measured)
#define RSTRIDE 257      // odd stride: LDS conflicts benign
#define KK2 4096         // tail candidate sort capacity (KCAP^2)

typedef unsigned long long ull;
typedef short bf16x8 __attribute__((ext_vector_type(8)));
typedef float f32x4  __attribute__((ext_vector_type(4)));

// ---------------- Kernel 1: batched S = A @ B^T via bf16 MFMA --------------
__device__ __forceinline__ unsigned bfpack2(float lo, float hi) {
  return (__float_as_uint(hi) & 0xFFFF0000u) | (__float_as_uint(lo) >> 16);
}

__global__ __launch_bounds__(256) void gemm_bt_mfma(const float* __restrict__ X1,
                                                    const float* __restrict__ X2,
                                                    float* __restrict__ S) {
  const int pair  = blockIdx.z;
  const int rbase = blockIdx.y * 128;
  const int cbase = blockIdx.x * 64;

  __shared__ unsigned short As[128][40];  // 32 k-vals + pad
  __shared__ unsigned short Bs[64][40];

  const int tid   = threadIdx.x;
  const int lane  = tid & 63;
  const int wave  = tid >> 6;
  const int q     = lane >> 4, mi = lane & 15;

  const int srowA = tid >> 1, halfA = tid & 1;
  const int srowB = tid >> 2, qB    = tid & 3;

  const float* Abase = X1 + (size_t)pair * NN * DD + (size_t)(rbase + srowA) * DD + halfA * 16;
  const float* Bbase = X2 + (size_t)pair * NN * DD + (size_t)(cbase + srowB) * DD + qB * 8;

  f32x4 acc[2][4] = {};

  float4 pa0, pa1, pa2, pa3, pb0, pb1;
  {
    const float4* ap = (const float4*)(Abase);
    const float4* bp = (const float4*)(Bbase);
    pa0 = ap[0]; pa1 = ap[1]; pa2 = ap[2]; pa3 = ap[3];
    pb0 = bp[0]; pb1 = bp[1];
  }

  for (int k0 = 0; k0 < DD; k0 += 32) {
    __syncthreads();
    {
      uint4 w0 = make_uint4(bfpack2(pa0.x,pa0.y), bfpack2(pa0.z,pa0.w),
                            bfpack2(pa1.x,pa1.y), bfpack2(pa1.z,pa1.w));
      uint4 w1 = make_uint4(bfpack2(pa2.x,pa2.y), bfpack2(pa2.z,pa2.w),
                            bfpack2(pa3.x,pa3.y), bfpack2(pa3.z,pa3.w));
      *(uint4*)&As[srowA][halfA*16]     = w0;
      *(uint4*)&As[srowA][halfA*16 + 8] = w1;
      uint4 v0 = make_uint4(bfpack2(pb0.x,pb0.y), bfpack2(pb0.z,pb0.w),
                            bfpack2(pb1.x,pb1.y), bfpack2(pb1.z,pb1.w));
      *(uint4*)&Bs[srowB][qB*8] = v0;
    }
    __syncthreads();
    const int kn = k0 + 32;
    if (kn < DD) {
      const float4* ap = (const float4*)(Abase + kn);
      const float4* bp = (const float4*)(Bbase + kn);
      pa0 = ap[0]; pa1 = ap[1]; pa2 = ap[2]; pa3 = ap[3];
      pb0 = bp[0]; pb1 = bp[1];
    }
    bf16x8 af[2], bf[4];
#pragma unroll
    for (int i = 0; i < 2; ++i) af[i] = *(const bf16x8*)&As[wave*32 + i*16 + mi][q*8];
#pragma unroll
    for (int j = 0; j < 4; ++j) bf[j] = *(const bf16x8*)&Bs[j*16 + mi][q*8];
#pragma unroll
    for (int i = 0; i < 2; ++i)
#pragma unroll
      for (int j = 0; j < 4; ++j)
        acc[i][j] = __builtin_amdgcn_mfma_f32_16x16x32_bf16(af[i], bf[j], acc[i][j], 0, 0, 0);
  }

  float* Sp = S + (size_t)pair * NN * NN;
#pragma unroll
  for (int i = 0; i < 2; ++i)
#pragma unroll
    for (int j = 0; j < 4; ++j)
#pragma unroll
      for (int r2 = 0; r2 < 4; ++r2) {
        const int rowg = rbase + wave*32 + i*16 + q*4 + r2;
        const int colg = cbase + j*16 + mi;
        Sp[(size_t)rowg * NN + colg] = acc[i][j][r2];
      }
}

// ---------------- DPP wave64 argmax (result in lane 63) --------------------
#define DPP_STEP(ctrl, rmask)                                                  \
  {                                                                            \
    int vi  = __float_as_int(v);                                               \
    int v2b = __builtin_amdgcn_update_dpp(vi, vi, (ctrl), (rmask), 0xf, false);\
    int i2  = __builtin_amdgcn_update_dpp(c,  c,  (ctrl), (rmask), 0xf, false);\
    float v2 = __int_as_float(v2b);                                            \
    if (v2 > v || (v2 == v && i2 < c)) { v = v2; c = i2; }                     \
  }

__device__ __forceinline__ void dpp_argmax(float& v, int& c) {
  DPP_STEP(0x111, 0xf)  // row_shr:1
  DPP_STEP(0x112, 0xf)  // row_shr:2
  DPP_STEP(0x114, 0xf)  // row_shr:4
  DPP_STEP(0x118, 0xf)  // row_shr:8
  DPP_STEP(0x142, 0xa)  // row_bcast:15
  DPP_STEP(0x143, 0xc)  // row_bcast:31
}
#undef DPP_STEP

__device__ __forceinline__ float rdlane_f(float v, int l) {
  return __int_as_float(__builtin_amdgcn_readlane(__float_as_int(v), l));
}

// i-th set bit (ascending) of a 256-bit mask; 0 if fewer than i+1 bits set
__device__ __forceinline__ int nth_set4(ull m0, ull m1, ull m2, ull m3, int n) {
  int base = 0; ull m = m0;
  int c = __popcll(m);
  if (n >= c) { n -= c; m = m1; base = 64; c = __popcll(m);
    if (n >= c) { n -= c; m = m2; base = 128; c = __popcll(m);
      if (n >= c) { n -= c; m = m3; base = 192; } } }
  for (int i = 0; i < n; ++i) m &= m - 1;
  return m ? (base + (int)__builtin_ctzll(m)) : 0;
}

// per-lane scan of its OWN row over alive cols (k>KCAP safety path only)
__device__ __forceinline__ void scan_own_row(const float* __restrict__ rowp,
                                             ull a0, ull a1, ull a2, ull a3,
                                             float& mv, int& ac) {
  float v = -INFINITY; int c = 0;
#pragma unroll
  for (int g = 0; g < 4; ++g) {
    const ull am = (g==0) ? a0 : (g==1) ? a1 : (g==2) ? a2 : a3;
#pragma unroll 8
    for (int j = 0; j < 64; ++j) {
      if ((am >> j) & 1ull) {
        const float x = rowp[g*64 + j];
        if (x > v) { v = x; c = g*64 + j; }
      }
    }
  }
  mv = v; ac = c;
}

// ------ Kernel 2: fully fused per-pair matcher, 1024 threads ---------------
// collect > THRESH -> bitonic 2048 -> wave-0 ordered ballot scan -> tail:
// gather alive rows, enumerate k*k, bitonic n2, wave-0 ballot scan. All
// state stays in LDS; one launch; pairs proceed independently.
__global__ __launch_bounds__(1024) void match_pair(const float* __restrict__ S,
                                                   float* __restrict__ out) {
  const int pair = blockIdx.x;
  const float* Sp = S + (size_t)pair * NN * NN;
  const int tid  = threadIdx.x;
  const int lane = tid & 63;
  const int wv   = tid >> 6;

  __shared__ ull keys2[KK2];               // 32 KB (phase A uses first CAPS)
  __shared__ float rows[KCAP * RSTRIDE];   // 65.8 KB
  __shared__ int lcount;
  __shared__ ull sh_mask[8];
  __shared__ float sh_sum;
  __shared__ int sh_picks;

  if (tid == 0) lcount = 0;
  __syncthreads();

  // ---- Phase A: collect entries > THRESH ----
  const float4* S4 = (const float4*)Sp;
#pragma unroll 4
  for (int i4 = tid; i4 < NN*NN/4; i4 += 1024) {
    float4 x = S4[i4];
    float xv[4] = {x.x, x.y, x.z, x.w};
#pragma unroll
    for (int e = 0; e < 4; ++e) {
      if (xv[e] > THRESH) {
        unsigned b = __float_as_uint(xv[e]);
        unsigned u = (b & 0x80000000u) ? ~b : (b | 0x80000000u);  // monotone asc
        int pos = atomicAdd(&lcount, 1);
        if (pos < CAPS)
          keys2[pos] = ((ull)(~u) << 32) | (unsigned)(i4*4 + e);
      }
    }
  }
  __syncthreads();
  int count = lcount;
  if (count > CAPS) count = 0;             // overflow => safe path below (k=256)
  for (int i = count + tid; i < CAPS; i += 1024) keys2[i] = ~0ull;
  __syncthreads();

  // ---- Phase A2: bitonic sort 2048 ascending (16 waves, all-block) ----
  for (unsigned kk = 2; kk <= CAPS; kk <<= 1)
    for (unsigned j = kk >> 1; j > 0; j >>= 1) {
      for (unsigned i = tid; i < CAPS; i += 1024) {
        unsigned ixj = i ^ j;
        if (ixj > i) {
          ull a = keys2[i], b = keys2[ixj];
          bool asc = ((i & kk) == 0);
          if ((a > b) == asc) { keys2[i] = b; keys2[ixj] = a; }
        }
      }
      __syncthreads();
    }

  // ---- Phase B: ordered ballot scan (wave 0 only) ----
  if (wv == 0) {
    unsigned rowAlive = 0xFu, colAlive = 0xFu;   // 4 rows/cols per lane
    float sum = 0.0f;
    int picks = 0;
    for (int base = 0; base < count && picks < NN; base += 64) {
      const ull key = keys2[base + lane];
      const int flat = (int)(unsigned)key;
      const int r = (flat >> 8) & 255, c = flat & 255;
      const unsigned u = ~(unsigned)(key >> 32);
      const float val = __uint_as_float((u & 0x80000000u) ? (u ^ 0x80000000u) : ~u);
      const bool valid = (base + lane) < count;

      const int rbits = __builtin_amdgcn_ds_bpermute((r & 63) << 2, (int)rowAlive);
      const int cbits = __builtin_amdgcn_ds_bpermute((c & 63) << 2, (int)colAlive);
      bool alive = valid && (((rbits >> (r >> 6)) & 1) != 0) && (((cbits >> (c >> 6)) & 1) != 0);

      while (true) {
        const ull mb = __ballot(alive);
        if (!mb) break;
        const int t   = __builtin_ctzll(mb);     // lowest lane = sorted order
        const int r_t = __builtin_amdgcn_readlane(r, t);
        const int c_t = __builtin_amdgcn_readlane(c, t);
        sum += rdlane_f(val, t);
        ++picks;
        alive = alive && (r != r_t) && (c != c_t);
        rowAlive &= ~((lane == (r_t & 63) ? 1u : 0u) << (r_t >> 6));
        colAlive &= ~((lane == (c_t & 63) ? 1u : 0u) << (c_t >> 6));
        if (picks == NN) break;
      }
    }
    ull m[8];
#pragma unroll
    for (int i = 0; i < 4; ++i) m[i]     = __ballot(((rowAlive >> i) & 1u) != 0);
#pragma unroll
    for (int i = 0; i < 4; ++i) m[4 + i] = __ballot(((colAlive >> i) & 1u) != 0);
    if (lane == 0) {
#pragma unroll
      for (int i = 0; i < 8; ++i) sh_mask[i] = m[i];
      sh_sum   = sum;
      sh_picks = picks;
    }
  }
  __syncthreads();

  const ull arow0 = sh_mask[0], arow1 = sh_mask[1], arow2 = sh_mask[2], arow3 = sh_mask[3];
  const ull acol0 = sh_mask[4], acol1 = sh_mask[5], acol2 = sh_mask[6], acol3 = sh_mask[7];
  float sum = sh_sum;
  const int picks = sh_picks;

  if (picks >= NN) {
    if (tid == 0) out[pair] = tanhf(sum / (float)NN);
    return;
  }
  const int k = NN - picks;

  if (k > KCAP) {
    // ---- safe path (never observed; count-overflow / k>64 net), wave 0 ----
    if (wv != 0) return;
    ull bc0 = acol0, bc1 = acol1, bc2 = acol2, bc3 = acol3;
    float rm[4]; int ra[4];
#pragma unroll
    for (int i = 0; i < 4; ++i) { rm[i] = -INFINITY; ra[i] = -1; }
    {
      if ((arow0 >> lane) & 1ull) scan_own_row(Sp + (size_t)lane * NN, bc0, bc1, bc2, bc3, rm[0], ra[0]);
      if ((arow1 >> lane) & 1ull) scan_own_row(Sp + (size_t)(64 + lane) * NN, bc0, bc1, bc2, bc3, rm[1], ra[1]);
      if ((arow2 >> lane) & 1ull) scan_own_row(Sp + (size_t)(128 + lane) * NN, bc0, bc1, bc2, bc3, rm[2], ra[2]);
      if ((arow3 >> lane) & 1ull) scan_own_row(Sp + (size_t)(192 + lane) * NN, bc0, bc1, bc2, bc3, rm[3], ra[3]);
    }
    for (int it = picks; it < NN; ++it) {
      float v = rm[0]; int c = lane;
      if (rm[1] > v) { v = rm[1]; c = 64 + lane; }
      if (rm[2] > v) { v = rm[2]; c = 128 + lane; }
      if (rm[3] > v) { v = rm[3]; c = 192 + lane; }
      dpp_argmax(v, c);
      const int br = __builtin_amdgcn_readlane(c, 63);
      sum += rdlane_f(v, 63);

      const int bslot = br >> 6, blane = br & 63;
      int myra = ra[0];
      if (bslot == 1) myra = ra[1];
      if (bslot == 2) myra = ra[2];
      if (bslot == 3) myra = ra[3];
      const int bc = __builtin_amdgcn_readlane(myra, blane);

      if (lane == blane) {
        if (bslot == 0) { rm[0] = -INFINITY; ra[0] = -1; }
        if (bslot == 1) { rm[1] = -INFINITY; ra[1] = -1; }
        if (bslot == 2) { rm[2] = -INFINITY; ra[2] = -1; }
        if (bslot == 3) { rm[3] = -INFINITY; ra[3] = -1; }
      }
      { const ull cb = ~(1ull << (bc & 63));
        if      (bc < 64)  bc0 &= cb;
        else if (bc < 128) bc1 &= cb;
        else if (bc < 192) bc2 &= cb;
        else               bc3 &= cb; }

#pragma unroll
      for (int i = 0; i < 4; ++i) {
        const bool st = (ra[i] == bc);
        if (__ballot(st)) {
          if (st) {
            float nv; int nc;
            scan_own_row(Sp + (size_t)(i*64 + lane) * NN, bc0, bc1, bc2, bc3, nv, nc);
            rm[i] = nv; ra[i] = nc;
          }
        }
      }
    }
    if (lane == 0) out[pair] = tanhf(sum / (float)NN);
    return;
  }

  // ---- Phase C: tail fast — gather rows, enumerate k*k, sort, scan ----
  const int slot = tid >> 4;               // 0..63 alive-row slot
  const int seg  = tid & 15;               // 16-col group within the row
  if (slot < k) {
    const int r = nth_set4(arow0, arow1, arow2, arow3, slot);
    const float4* src = (const float4*)(Sp + (size_t)r * NN + seg * 16);
    float* dst = &rows[slot * RSTRIDE + seg * 16];
#pragma unroll
    for (int i = 0; i < 4; ++i) {
      float4 v = src[i];
      dst[i*4 + 0] = v.x; dst[i*4 + 1] = v.y;
      dst[i*4 + 2] = v.z; dst[i*4 + 3] = v.w;
    }
    // enumerate this thread's 16-col group (reads only its OWN rows writes)
    const int w  = seg >> 2;               // acol word of this 16-col group
    const int sb = (seg & 3) * 16;         // start bit within the word
    const ull aw = (w==0) ? acol0 : (w==1) ? acol1 : (w==2) ? acol2 : acol3;
    int crank = 0;
    if (w > 0) crank += __popcll(acol0);
    if (w > 1) crank += __popcll(acol1);
    if (w > 2) crank += __popcll(acol2);
    crank += __popcll(aw & ((1ull << sb) - 1ull));
    const float* rp = &rows[slot * RSTRIDE + w * 64];
    for (int j = sb; j < sb + 16; ++j) {
      if ((aw >> j) & 1ull) {
        const unsigned b = __float_as_uint(rp[j]);
        const unsigned u = (b & 0x80000000u) ? ~b : (b | 0x80000000u);
        keys2[slot * k + crank] = ((ull)(~u) << 32) | (unsigned)((slot << 6) | crank);
        ++crank;
      }
    }
  }
  const int nkk = k * k;
  int n2 = 64; while (n2 < nkk) n2 <<= 1;  // runtime sort size (<= 4096)
  for (int i = nkk + tid; i < n2; i += 1024) keys2[i] = ~0ull;  // pad
  __syncthreads();

  // all-block bitonic sort (runtime n2)
  for (unsigned kk = 2; kk <= (unsigned)n2; kk <<= 1)
    for (unsigned j = kk >> 1; j > 0; j >>= 1) {
      for (unsigned i = tid; i < (unsigned)n2; i += 1024) {
        unsigned ixj = i ^ j;
        if (ixj > i) {
          ull a = keys2[i], b = keys2[ixj];
          bool asc = ((i & kk) == 0);
          if ((a > b) == asc) { keys2[i] = b; keys2[ixj] = a; }
        }
      }
      __syncthreads();
    }
  if (wv != 0) return;                     // wave 0 scans alone

  // ballot compare-kill scan over sorted k*k entries
  ull rAlive = (k == 64) ? ~0ull : ((1ull << k) - 1ull);
  ull cAlive = rAlive;
  int tpicks = 0;
  for (int base = 0; base < nkk && tpicks < k; base += 64) {
    const ull key = keys2[base + lane];
    const int rc = (int)(unsigned)key & 0xFFF;
    const int rs = (rc >> 6) & 63, cs = rc & 63;
    const unsigned u = ~(unsigned)(key >> 32);
    const float val = __uint_as_float((u & 0x80000000u) ? (u ^ 0x80000000u) : ~u);
    const bool valid = (base + lane) < nkk;

    bool alive = valid && (((rAlive >> rs) & 1ull) != 0) && (((cAlive >> cs) & 1ull) != 0);
    while (true) {
      const ull mb = __ballot(alive);
      if (!mb) break;
      const int t    = __builtin_ctzll(mb);    // lowest lane = sorted order
      const int rs_t = __builtin_amdgcn_readlane(rs, t);
      const int cs_t = __builtin_amdgcn_readlane(cs, t);
      sum += rdlane_f(val, t);
      ++tpicks;
      alive = alive && (rs != rs_t) && (cs != cs_t);
      rAlive &= ~(1ull << rs_t);
      cAlive &= ~(1ull << cs_t);
      if (tpicks == k) break;
    }
  }

  if (lane == 0) out[pair] = tanhf(sum / (float)NN);
}

extern "C" void kernel_launch(void* const* d_in, const int* in_sizes, int n_in,
                              void* d_out, int out_size, void* d_ws, size_t ws_size,
                              hipStream_t stream) {
  const float* x1 = (const float*)d_in[0];
  const float* x2 = (const float*)d_in[1];
  float* out = (float*)d_out;
  float* S   = (float*)d_ws;           // B*N*N*4 = 32 MiB

  const int B = in_sizes[0] / (NN * DD);

  dim3 ggrid(NN / 64, NN / 128, B);    // 4 x 2 x 128 = 1024 blocks
  gemm_bt_mfma<<<ggrid, 256, 0, stream>>>(x1, x2, S);
  match_pair<<<B, 1024, 0, stream>>>(S, out);
}

// Round 9
// 253.248 us; speedup vs baseline: 2.4223x; 1.0697x over previous
//
#include <hip/hip_runtime.h>
#include <cmath>

// MNEMatch: B pairs of [N,D] fp32; S = x1 @ x2^T per pair; greedy max matching
// (== sort entries desc + scan taking row/col-free entries); out[b]=tanh(sum/N).
// Fully fused: one block per pair does GEMM (MFMA) + collect + sort + scan + tail.
#define NN 256
#define DD 384
#define CAPS 2048        // sorted candidate capacity (mean ~1350 at T=40)
#define THRESH 40.0f     // ~2.04 sigma of N(0,384)
#define KCAP 64          // tail fast-path capacity (k mean ~23, max < 64 measured)
#define RSTRIDE 257      // odd stride: LDS conflicts benign
#define KK2 4096         // tail candidate sort capacity (KCAP^2)

typedef unsigned long long ull;
typedef short bf16x8 __attribute__((ext_vector_type(8)));
typedef float f32x4  __attribute__((ext_vector_type(4)));

__device__ __forceinline__ unsigned bfpack2(float lo, float hi) {
  return (__float_as_uint(hi) & 0xFFFF0000u) | (__float_as_uint(lo) >> 16);
}

// ---------------- DPP wave64 argmax (result in lane 63) --------------------
#define DPP_STEP(ctrl, rmask)                                                  \
  {                                                                            \
    int vi  = __float_as_int(v);                                               \
    int v2b = __builtin_amdgcn_update_dpp(vi, vi, (ctrl), (rmask), 0xf, false);\
    int i2  = __builtin_amdgcn_update_dpp(c,  c,  (ctrl), (rmask), 0xf, false);\
    float v2 = __int_as_float(v2b);                                            \
    if (v2 > v || (v2 == v && i2 < c)) { v = v2; c = i2; }                     \
  }

__device__ __forceinline__ void dpp_argmax(float& v, int& c) {
  DPP_STEP(0x111, 0xf)  // row_shr:1
  DPP_STEP(0x112, 0xf)  // row_shr:2
  DPP_STEP(0x114, 0xf)  // row_shr:4
  DPP_STEP(0x118, 0xf)  // row_shr:8
  DPP_STEP(0x142, 0xa)  // row_bcast:15
  DPP_STEP(0x143, 0xc)  // row_bcast:31
}
#undef DPP_STEP

__device__ __forceinline__ float rdlane_f(float v, int l) {
  return __int_as_float(__builtin_amdgcn_readlane(__float_as_int(v), l));
}

// i-th set bit (ascending) of a 256-bit mask; 0 if fewer than i+1 bits set
__device__ __forceinline__ int nth_set4(ull m0, ull m1, ull m2, ull m3, int n) {
  int base = 0; ull m = m0;
  int c = __popcll(m);
  if (n >= c) { n -= c; m = m1; base = 64; c = __popcll(m);
    if (n >= c) { n -= c; m = m2; base = 128; c = __popcll(m);
      if (n >= c) { n -= c; m = m3; base = 192; } } }
  for (int i = 0; i < n; ++i) m &= m - 1;
  return m ? (base + (int)__builtin_ctzll(m)) : 0;
}

// per-lane scan of its OWN row over alive cols (k>KCAP safety path only)
__device__ __forceinline__ void scan_own_row(const float* __restrict__ rowp,
                                             ull a0, ull a1, ull a2, ull a3,
                                             float& mv, int& ac) {
  float v = -INFINITY; int c = 0;
#pragma unroll
  for (int g = 0; g < 4; ++g) {
    const ull am = (g==0) ? a0 : (g==1) ? a1 : (g==2) ? a2 : a3;
#pragma unroll 8
    for (int j = 0; j < 64; ++j) {
      if ((am >> j) & 1ull) {
        const float x = rowp[g*64 + j];
        if (x > v) { v = x; c = g*64 + j; }
      }
    }
  }
  mv = v; ac = c;
}

// ---- wave-chunked bitonic sort of n (pow2) ull keys in LDS, 16 waves ------
// Steps with compare distance < chunk run wave-synchronously (in-order LDS
// pipe + wave_barrier); only j >= chunk steps + kk transitions block-sync.
// Same compare-exchange network as the monolithic version => same result.
__device__ __forceinline__ void bitonic_lds(ull* __restrict__ keys, int n,
                                            int tid, int lane, int wv) {
  const int chunk = ((n >> 4) < 64) ? 64 : (n >> 4);
  const int wbase = wv * chunk;

#define CMPSW(I, KK)                                                           \
  {                                                                            \
    int ixj = (I) ^ j;                                                         \
    if (ixj > (I)) {                                                           \
      ull a = keys[(I)], b = keys[ixj];                                        \
      bool asc = (((I) & (KK)) == 0);                                          \
      if ((a > b) == asc) { keys[(I)] = b; keys[ixj] = a; }                    \
    }                                                                          \
  }

  // local region: kk = 2..chunk entirely within one wave's chunk
  if (wbase < n) {
    for (int kk = 2; kk <= chunk; kk <<= 1)
      for (int j = kk >> 1; j > 0; j >>= 1) {
        for (int t = lane; t < chunk; t += 64) { int i = wbase + t; CMPSW(i, kk) }
        __builtin_amdgcn_wave_barrier();
      }
  }
  __syncthreads();
  for (int kk = chunk << 1; kk <= n; kk <<= 1) {
    for (int j = kk >> 1; j >= chunk; j >>= 1) {
      for (int i = tid; i < n; i += 1024) CMPSW(i, kk)
      __syncthreads();
    }
    if (wbase < n) {
      for (int j = chunk >> 1; j > 0; j >>= 1) {
        for (int t = lane; t < chunk; t += 64) { int i = wbase + t; CMPSW(i, kk) }
        __builtin_amdgcn_wave_barrier();
      }
    }
    __syncthreads();
  }
#undef CMPSW
}

// ------ THE kernel: per-pair GEMM + collect + sort + scan + tail -----------
__global__ __launch_bounds__(1024) void match_pair(const float* __restrict__ X1,
                                                   const float* __restrict__ X2,
                                                   float* __restrict__ S,
                                                   float* __restrict__ out) {
  const int pair = blockIdx.x;
  const int tid  = threadIdx.x;
  const int lane = tid & 63;
  const int wv   = tid >> 6;

  __shared__ float rows[KCAP * RSTRIDE];   // 65.8 KB (gemm staging aliased here)
  __shared__ ull keys2[KK2];               // 32 KB (collect uses first CAPS)
  __shared__ int lcount;
  __shared__ ull sh_mask[8];
  __shared__ float sh_sum;
  __shared__ int sh_picks;

  const float* X1p = X1 + (size_t)pair * NN * DD;
  const float* X2p = X2 + (size_t)pair * NN * DD;
  float* Sp = S + (size_t)pair * NN * NN;

  if (tid == 0) lcount = 0;

  // ---- Phase G: inline GEMM (MFMA) + S store + collect from accumulators --
  // 2 col-passes of 128 cols; wave w owns rows 16w..16w+15 (acc 8 tiles of
  // 16x16 = 32 VGPR). Same MFMA + same K-order as the old gemm kernel =>
  // bitwise-identical S.
  {
    unsigned short (*As)[40] = (unsigned short(*)[40])rows;            // 256x40
    unsigned short (*Bs)[40] = (unsigned short(*)[40])(rows + 5120);   // 128x40
    const int q  = lane >> 4, mi = lane & 15;
    const int srA = tid >> 2, qkA = tid & 3;        // A: 256 rows x 32k, 8 f/thread
    const int srB = tid >> 3, qkB = tid & 7;        // B: 128 rows x 32k, 4 f/thread
    const float* aptr = X1p + (size_t)srA * DD + qkA * 8;

    for (int pass = 0; pass < 2; ++pass) {
      const int colbase = pass * 128;
      const float* bptr = X2p + (size_t)(colbase + srB) * DD + qkB * 4;

      f32x4 acc[8] = {};
      float4 pa0 = *(const float4*)(aptr);
      float4 pa1 = *(const float4*)(aptr + 4);
      float4 pb0 = *(const float4*)(bptr);

      for (int k0 = 0; k0 < DD; k0 += 32) {
        __syncthreads();
        {
          uint4 wA = make_uint4(bfpack2(pa0.x,pa0.y), bfpack2(pa0.z,pa0.w),
                                bfpack2(pa1.x,pa1.y), bfpack2(pa1.z,pa1.w));
          *(uint4*)&As[srA][qkA*8] = wA;
          uint2 wB = make_uint2(bfpack2(pb0.x,pb0.y), bfpack2(pb0.z,pb0.w));
          *(uint2*)&Bs[srB][qkB*4] = wB;
        }
        __syncthreads();
        const int kn = k0 + 32;
        if (kn < DD) {                      // prefetch next K-slab
          pa0 = *(const float4*)(aptr + kn);
          pa1 = *(const float4*)(aptr + kn + 4);
          pb0 = *(const float4*)(bptr + kn);
        }
        bf16x8 af = *(const bf16x8*)&As[wv*16 + mi][q*8];
#pragma unroll
        for (int t = 0; t < 8; ++t) {
          bf16x8 bf = *(const bf16x8*)&Bs[t*16 + mi][q*8];
          acc[t] = __builtin_amdgcn_mfma_f32_16x16x32_bf16(af, bf, acc[t], 0, 0, 0);
        }
      }
      // store S + collect candidates straight from acc
#pragma unroll
      for (int t = 0; t < 8; ++t)
#pragma unroll
        for (int r = 0; r < 4; ++r) {
          const int rowg = wv*16 + q*4 + r;       // C/D: row = quad*4+reg
          const int colg = colbase + t*16 + mi;   //      col = lane&15
          const float v = acc[t][r];
          Sp[(size_t)rowg * NN + colg] = v;
          if (v > THRESH) {
            unsigned b = __float_as_uint(v);
            unsigned u = (b & 0x80000000u) ? ~b : (b | 0x80000000u);  // monotone asc
            int pos = atomicAdd(&lcount, 1);
            if (pos < CAPS)
              keys2[pos] = ((ull)(~u) << 32) | (unsigned)(rowg * NN + colg);
          }
        }
      __syncthreads();   // staging buffers free for next pass / later phases
    }
  }

  int count = lcount;
  if (count > CAPS) count = 0;             // overflow => safe path below (k=256)
  for (int i = count + tid; i < CAPS; i += 1024) keys2[i] = ~0ull;
  __syncthreads();

  // ---- Phase A2: bitonic sort 2048 ascending (wave-chunked) ----
  bitonic_lds(keys2, CAPS, tid, lane, wv);

  // ---- Phase B: ordered ballot scan (wave 0 only) ----
  if (wv == 0) {
    unsigned rowAlive = 0xFu, colAlive = 0xFu;   // 4 rows/cols per lane
    float sum = 0.0f;
    int picks = 0;
    for (int base = 0; base < count && picks < NN; base += 64) {
      const ull key = keys2[base + lane];
      const int flat = (int)(unsigned)key;
      const int r = (flat >> 8) & 255, c = flat & 255;
      const unsigned u = ~(unsigned)(key >> 32);
      const float val = __uint_as_float((u & 0x80000000u) ? (u ^ 0x80000000u) : ~u);
      const bool valid = (base + lane) < count;

      const int rbits = __builtin_amdgcn_ds_bpermute((r & 63) << 2, (int)rowAlive);
      const int cbits = __builtin_amdgcn_ds_bpermute((c & 63) << 2, (int)colAlive);
      bool alive = valid && (((rbits >> (r >> 6)) & 1) != 0) && (((cbits >> (c >> 6)) & 1) != 0);

      while (true) {
        const ull mb = __ballot(alive);
        if (!mb) break;
        const int t   = __builtin_ctzll(mb);     // lowest lane = sorted order
        const int r_t = __builtin_amdgcn_readlane(r, t);
        const int c_t = __builtin_amdgcn_readlane(c, t);
        sum += rdlane_f(val, t);
        ++picks;
        alive = alive && (r != r_t) && (c != c_t);
        rowAlive &= ~((lane == (r_t & 63) ? 1u : 0u) << (r_t >> 6));
        colAlive &= ~((lane == (c_t & 63) ? 1u : 0u) << (c_t >> 6));
        if (picks == NN) break;
      }
    }
    ull m[8];
#pragma unroll
    for (int i = 0; i < 4; ++i) m[i]     = __ballot(((rowAlive >> i) & 1u) != 0);
#pragma unroll
    for (int i = 0; i < 4; ++i) m[4 + i] = __ballot(((colAlive >> i) & 1u) != 0);
    if (lane == 0) {
#pragma unroll
      for (int i = 0; i < 8; ++i) sh_mask[i] = m[i];
      sh_sum   = sum;
      sh_picks = picks;
    }
  }
  __syncthreads();

  const ull arow0 = sh_mask[0], arow1 = sh_mask[1], arow2 = sh_mask[2], arow3 = sh_mask[3];
  const ull acol0 = sh_mask[4], acol1 = sh_mask[5], acol2 = sh_mask[6], acol3 = sh_mask[7];
  float sum = sh_sum;
  const int picks = sh_picks;

  if (picks >= NN) {
    if (tid == 0) out[pair] = tanhf(sum / (float)NN);
    return;
  }
  const int k = NN - picks;

  if (k > KCAP) {
    // ---- safe path (count-overflow / k>64 net; never observed), wave 0 ----
    if (wv != 0) return;
    ull bc0 = acol0, bc1 = acol1, bc2 = acol2, bc3 = acol3;
    float rm[4]; int ra[4];
#pragma unroll
    for (int i = 0; i < 4; ++i) { rm[i] = -INFINITY; ra[i] = -1; }
    {
      if ((arow0 >> lane) & 1ull) scan_own_row(Sp + (size_t)lane * NN, bc0, bc1, bc2, bc3, rm[0], ra[0]);
      if ((arow1 >> lane) & 1ull) scan_own_row(Sp + (size_t)(64 + lane) * NN, bc0, bc1, bc2, bc3, rm[1], ra[1]);
      if ((arow2 >> lane) & 1ull) scan_own_row(Sp + (size_t)(128 + lane) * NN, bc0, bc1, bc2, bc3, rm[2], ra[2]);
      if ((arow3 >> lane) & 1ull) scan_own_row(Sp + (size_t)(192 + lane) * NN, bc0, bc1, bc2, bc3, rm[3], ra[3]);
    }
    for (int it = picks; it < NN; ++it) {
      float v = rm[0]; int c = lane;
      if (rm[1] > v) { v = rm[1]; c = 64 + lane; }
      if (rm[2] > v) { v = rm[2]; c = 128 + lane; }
      if (rm[3] > v) { v = rm[3]; c = 192 + lane; }
      dpp_argmax(v, c);
      const int br = __builtin_amdgcn_readlane(c, 63);
      sum += rdlane_f(v, 63);

      const int bslot = br >> 6, blane = br & 63;
      int myra = ra[0];
      if (bslot == 1) myra = ra[1];
      if (bslot == 2) myra = ra[2];
      if (bslot == 3) myra = ra[3];
      const int bc = __builtin_amdgcn_readlane(myra, blane);

      if (lane == blane) {
        if (bslot == 0) { rm[0] = -INFINITY; ra[0] = -1; }
        if (bslot == 1) { rm[1] = -INFINITY; ra[1] = -1; }
        if (bslot == 2) { rm[2] = -INFINITY; ra[2] = -1; }
        if (bslot == 3) { rm[3] = -INFINITY; ra[3] = -1; }
      }
      { const ull cb = ~(1ull << (bc & 63));
        if      (bc < 64)  bc0 &= cb;
        else if (bc < 128) bc1 &= cb;
        else if (bc < 192) bc2 &= cb;
        else               bc3 &= cb; }

#pragma unroll
      for (int i = 0; i < 4; ++i) {
        const bool st = (ra[i] == bc);
        if (__ballot(st)) {
          if (st) {
            float nv; int nc;
            scan_own_row(Sp + (size_t)(i*64 + lane) * NN, bc0, bc1, bc2, bc3, nv, nc);
            rm[i] = nv; ra[i] = nc;
          }
        }
      }
    }
    if (lane == 0) out[pair] = tanhf(sum / (float)NN);
    return;
  }

  // ---- Phase C: tail fast — gather rows, enumerate k*k, sort, scan ----
  const int slot = tid >> 4;               // 0..63 alive-row slot
  const int seg  = tid & 15;               // 16-col group within the row
  if (slot < k) {
    const int r = nth_set4(arow0, arow1, arow2, arow3, slot);
    const float4* src = (const float4*)(Sp + (size_t)r * NN + seg * 16);
    float* dst = &rows[slot * RSTRIDE + seg * 16];
#pragma unroll
    for (int i = 0; i < 4; ++i) {
      float4 v = src[i];
      dst[i*4 + 0] = v.x; dst[i*4 + 1] = v.y;
      dst[i*4 + 2] = v.z; dst[i*4 + 3] = v.w;
    }
    // enumerate this thread's 16-col group (reads only its OWN writes)
    const int w  = seg >> 2;               // acol word of this 16-col group
    const int sb = (seg & 3) * 16;         // start bit within the word
    const ull aw = (w==0) ? acol0 : (w==1) ? acol1 : (w==2) ? acol2 : acol3;
    int crank = 0;
    if (w > 0) crank += __popcll(acol0);
    if (w > 1) crank += __popcll(acol1);
    if (w > 2) crank += __popcll(acol2);
    crank += __popcll(aw & ((1ull << sb) - 1ull));
    const float* rp = &rows[slot * RSTRIDE + w * 64];
    for (int j = sb; j < sb + 16; ++j) {
      if ((aw >> j) & 1ull) {
        const unsigned b = __float_as_uint(rp[j]);
        const unsigned u = (b & 0x80000000u) ? ~b : (b | 0x80000000u);
        keys2[slot * k + crank] = ((ull)(~u) << 32) | (unsigned)((slot << 6) | crank);
        ++crank;
      }
    }
  }
  const int nkk = k * k;
  int n2 = 64; while (n2 < nkk) n2 <<= 1;  // runtime sort size (<= 4096)
  for (int i = nkk + tid; i < n2; i += 1024) keys2[i] = ~0ull;  // pad
  __syncthreads();

  bitonic_lds(keys2, n2, tid, lane, wv);

  if (wv != 0) return;                     // wave 0 scans alone

  // ballot compare-kill scan over sorted k*k entries
  ull rAlive = (k == 64) ? ~0ull : ((1ull << k) - 1ull);
  ull cAlive = rAlive;
  int tpicks = 0;
  for (int base = 0; base < nkk && tpicks < k; base += 64) {
    const ull key = keys2[base + lane];
    const int rc = (int)(unsigned)key & 0xFFF;
    const int rs = (rc >> 6) & 63, cs = rc & 63;
    const unsigned u = ~(unsigned)(key >> 32);
    const float val = __uint_as_float((u & 0x80000000u) ? (u ^ 0x80000000u) : ~u);
    const bool valid = (base + lane) < nkk;

    bool alive = valid && (((rAlive >> rs) & 1ull) != 0) && (((cAlive >> cs) & 1ull) != 0);
    while (true) {
      const ull mb = __ballot(alive);
      if (!mb) break;
      const int t    = __builtin_ctzll(mb);    // lowest lane = sorted order
      const int rs_t = __builtin_amdgcn_readlane(rs, t);
      const int cs_t = __builtin_amdgcn_readlane(cs, t);
      sum += rdlane_f(val, t);
      ++tpicks;
      alive = alive && (rs != rs_t) && (cs != cs_t);
      rAlive &= ~(1ull << rs_t);
      cAlive &= ~(1ull << cs_t);
      if (tpicks == k) break;
    }
  }

  if (lane == 0) out[pair] = tanhf(sum / (float)NN);
}

extern "C" void kernel_launch(void* const* d_in, const int* in_sizes, int n_in,
                              void* d_out, int out_size, void* d_ws, size_t ws_size,
                              hipStream_t stream) {
  const float* x1 = (const float*)d_in[0];
  const float* x2 = (const float*)d_in[1];
  float* out = (float*)d_out;
  float* S   = (float*)d_ws;           // B*N*N*4 = 32 MiB (tail gather + safe path)

  const int B = in_sizes[0] / (NN * DD);

  match_pair<<<B, 1024, 0, stream>>>(x1, x2, S, out);
}